// Round 5
// baseline (614.489 us; speedup 1.0000x reference)
//
#include <hip/hip_runtime.h>
#include <cstdint>
#include <cstddef>

typedef unsigned int   u32;
typedef unsigned short u16;

__device__ __forceinline__ float bf2f(u32 bits16) { return __uint_as_float(bits16 << 16); }
__device__ __forceinline__ u16 f2bf(float f) {
  u32 u = __float_as_uint(f);
  u = u + 0x7FFFu + ((u >> 16) & 1u);   // round-to-nearest-even
  return (u16)(u >> 16);
}
__device__ __forceinline__ u32 pk(float a, float b) {
  return (u32)f2bf(a) | ((u32)f2bf(b) << 16);
}
__device__ __forceinline__ float lo16(u32 w) { return bf2f(w & 0xFFFFu); }
__device__ __forceinline__ float hi16(u32 w) { return bf2f(w >> 16); }
__device__ __forceinline__ float frcp(float x) { return __builtin_amdgcn_rcpf(x); }

#define NL2E  (-1.4426950408889634f)
#define TWOL2E (2.8853900817779268f)

__device__ __forceinline__ int load_idx(const int* eidx, int is64, long long pos) {
  if (is64) return (int)(((const long long*)eidx)[pos]);
  return eidx[pos];
}

// ---- prep stage 1 (grid 34): WcTmp = Wvl_left @ Wvv, edge-width detect, bc ----
__global__ void k_prep1(const float* Wvl, const float* Wvv,
                        const float* bvv, const float* bvl,
                        const int* eidx, int E, int* flag,
                        float* WcTmp, float* bc) {
  int b = blockIdx.x, tid = threadIdx.x;
  if (b < 32) {
    int c = 2 * b + (tid >> 7), kk = tid & 127;
    float s = 0.f;
    for (int m = 0; m < 64; ++m) s += Wvl[c * 128 + m] * Wvv[m * 128 + kk];
    WcTmp[c * 128 + kk] = s;
  } else if (b == 32) {
    __shared__ int zc;
    if (tid == 0) zc = 0;
    __syncthreads();
    int n = (E < 1024) ? E : 1024;
    int local = 0;
    for (int i = tid; i < n; i += 256) {
      if (eidx[2 * i + 1] == 0) local++;   // high words if int64 (all 0)
    }
    atomicAdd(&zc, local);
    __syncthreads();
    if (tid == 0) *flag = (zc >= (n >> 1)) ? 1 : 0;
  } else if (b == 33) {
    if (tid < 64) {
      float s = 0.f;
      for (int m = 0; m < 64; ++m) s += Wvl[tid * 128 + m] * bvv[m];
      bc[tid] = s + bvl[tid];
    }
  }
}

// ---- prep stage 2 (grid 11): bf16 epilogue tables + interleaved GEMM weight table ----
// Wsl2[(g*64+c)*2+h] = pack(Wsl[c][4g+2h], Wsl[c][4g+2h+1]), g<32
// Wpk : 2048 u32 : Wvl_right packed, same (g,c,h) layout, g<16
// WTall[((y*64+k)*64+c)*4+m]: m0=Wss[c][64y+k] m1=Wsv[..] m2=Wvs[..] m3=WcTmp[..]
__global__ void k_prep2(const float* Wss, const float* Wsv, const float* Wvs,
                        const float* Wsl, const float* Wvl, const float* WcTmp,
                        u32* Wsl2, u32* Wpk, float* WTall) {
  int b = blockIdx.x, tid = threadIdx.x;
  if (b < 2) {
    for (int i = 0; i < 8; ++i) {
      int o = b * 2048 + i * 256 + tid;
      int h = o & 1, c = (o >> 1) & 63, g = o >> 7;
      int k = 4 * g + 2 * h;
      Wsl2[o] = pk(Wsl[c * 128 + k], Wsl[c * 128 + k + 1]);
    }
  } else if (b == 2) {
    for (int i = 0; i < 8; ++i) {
      int o = i * 256 + tid;
      int h = o & 1, c = (o >> 1) & 63, g = o >> 7;
      int k = 4 * g + 2 * h;
      Wpk[o] = pk(Wvl[c * 128 + 64 + k], Wvl[c * 128 + 64 + k + 1]);
    }
  } else {
    for (int i = 0; i < 16; ++i) {
      int o = (b - 3) * 4096 + i * 256 + tid;
      int m = o & 3, c = (o >> 2) & 63, k = (o >> 8) & 63, y = o >> 14;
      int src = c * 128 + 64 * y + k;
      float v;
      if (m == 0)      v = Wss[src];
      else if (m == 1) v = Wsv[src];
      else if (m == 2) v = Wvs[src];
      else             v = WcTmp[src];
      WTall[o] = v;
    }
  }
}

__global__ void k_deg(const int* eidx, const int* flag, const float* attr,
                      float* deg, int* cnt, int E) {
  int e = blockIdx.x * 256 + threadIdx.x;
  if (e >= E) return;
  int is64 = *flag;
  int col = load_idx(eidx, is64, (long long)E + e);
  atomicAdd(&deg[col], attr[e]);
  atomicAdd(&cnt[col], 1);
}

// ---- multi-block exclusive scan of cnt -> rowptr, cursor ----
__global__ void k_scan_red(const int* cnt, int* blocksum, int N) {
  __shared__ int lds[256];
  int tid = threadIdx.x, idx = blockIdx.x * 256 + tid;
  lds[tid] = (idx < N) ? cnt[idx] : 0;
  __syncthreads();
  for (int off = 128; off > 0; off >>= 1) {
    if (tid < off) lds[tid] += lds[tid + off];
    __syncthreads();
  }
  if (tid == 0) blocksum[blockIdx.x] = lds[0];
}

__global__ void k_scan_mid(const int* blocksum, int* blockoff, int NB, int* rowptr, int N, int E) {
  __shared__ int lds[1024];
  int tid = threadIdx.x;
  int v = (tid < NB) ? blocksum[tid] : 0;
  lds[tid] = v;
  __syncthreads();
  for (int off = 1; off < 1024; off <<= 1) {
    int t = (tid >= off) ? lds[tid - off] : 0;
    __syncthreads();
    lds[tid] += t;
    __syncthreads();
  }
  if (tid < NB) blockoff[tid] = lds[tid] - v;   // exclusive
  if (tid == 0) rowptr[N] = E;
}

__global__ void k_scan_out(const int* cnt, const int* blockoff, int* rowptr, int* cursor, int N) {
  __shared__ int lds[256];
  int tid = threadIdx.x, idx = blockIdx.x * 256 + tid;
  int v = (idx < N) ? cnt[idx] : 0;
  lds[tid] = v;
  __syncthreads();
  for (int off = 1; off < 256; off <<= 1) {
    int t = (tid >= off) ? lds[tid - off] : 0;
    __syncthreads();
    lds[tid] += t;
    __syncthreads();
  }
  if (idx < N) {
    int o = blockoff[blockIdx.x] + lds[tid] - v;
    rowptr[idx] = o;
    cursor[idx] = o;
  }
}

// CSR fill: erecA[p]={norm, dx, dy, dz} (d = pos_i - pos_j), erecI[p]=row
__global__ void k_fill(const int* eidx, const int* flag, const float* attr, const float* deg,
                       const float* pos, int* cursor, float4* erecA, int* erecI, int E) {
  int e = blockIdx.x * 256 + threadIdx.x;
  if (e >= E) return;
  int is64 = *flag;
  int r  = load_idx(eidx, is64, e);
  int cl = load_idx(eidx, is64, (long long)E + e);
  float dr = deg[r], dc = deg[cl];
  float disr = (dr > 0.f) ? rsqrtf(dr) : 0.f;
  float disc = (dc > 0.f) ? rsqrtf(dc) : 0.f;
  float nrm = disr * disc * attr[e];
  float dx = pos[cl * 3 + 0] - pos[r * 3 + 0];
  float dy = pos[cl * 3 + 1] - pos[r * 3 + 1];
  float dz = pos[cl * 3 + 2] - pos[r * 3 + 2];
  int p = atomicAdd(&cursor[cl], 1);
  erecA[p] = make_float4(nrm, dx, dy, dz);
  erecI[p] = r;
}

// Fused node GEMM v5: X staged once in LDS (34 KB), W read straight from
// global (coalesced 256B segments, L1/L2-hot, no staging barriers).
// grid ceil(N/32): 256 threads, thread (ng=tid>>4, cg=tid&15) owns nodes
// {ng, ng+16} x channels {cg,16+cg,32+cg,48+cg}. 1 barrier total.
// 4 blocks/CU (LDS 34KB, VGPR<=128 via launch_bounds), 64 accum chains/thread.
__global__ __launch_bounds__(256, 4) void k_gemm_rec(
    const float* __restrict__ scalar, const float* __restrict__ vector,
    const float* __restrict__ WTall,
    uint4* __restrict__ rec_i4, uint4* __restrict__ rec_j4, int N) {
  __shared__ float Xs[4][32][68];   // 34816 B
  int tid = threadIdx.x;
  int nb = blockIdx.x * 32;
  #pragma unroll
  for (int i = 0; i < 2; ++i) {
    int q = tid + i * 256;            // q = n*16 + kq
    int n = q >> 4, kq = q & 15;
    float4 v = make_float4(0.f, 0.f, 0.f, 0.f);
    if (nb + n < N) v = *(const float4*)(scalar + (size_t)(nb + n) * 64 + 4 * kq);
    *(float4*)&Xs[0][n][4 * kq] = v;
  }
  #pragma unroll
  for (int i = 0; i < 6; ++i) {
    int q = tid + i * 256;            // q = (n*3+d)*16 + kq
    int r = q >> 4, kq = q & 15;
    int n = r / 3, d = r - n * 3;
    float4 v = make_float4(0.f, 0.f, 0.f, 0.f);
    if (nb + n < N) v = *(const float4*)(vector + (size_t)(nb + n) * 192 + d * 64 + 4 * kq);
    *(float4*)&Xs[1 + d][n][4 * kq] = v;
  }
  __syncthreads();

  int cg = tid & 15, ng = tid >> 4;
  #pragma unroll
  for (int y = 0; y < 2; ++y) {
    float aA[2][4] = {}, aC[2][4] = {};
    float aB[2][3][4] = {}, aP[2][3][4] = {};
    const float4* Wg = (const float4*)WTall + (size_t)y * 4096;
    for (int k4 = 0; k4 < 64; k4 += 4) {
      float4 x0[2], x1[2], x2[2], x3[2];
      #pragma unroll
      for (int r = 0; r < 2; ++r) {
        int n = ng + 16 * r;
        x0[r] = *(const float4*)&Xs[0][n][k4];
        x1[r] = *(const float4*)&Xs[1][n][k4];
        x2[r] = *(const float4*)&Xs[2][n][k4];
        x3[r] = *(const float4*)&Xs[3][n][k4];
      }
      #pragma unroll
      for (int t = 0; t < 4; ++t) {
        #pragma unroll
        for (int j = 0; j < 4; ++j) {
          float4 w = Wg[(k4 + t) * 64 + 16 * j + cg];
          #pragma unroll
          for (int r = 0; r < 2; ++r) {
            float xsv = (t == 0) ? x0[r].x : (t == 1) ? x0[r].y : (t == 2) ? x0[r].z : x0[r].w;
            float xv0 = (t == 0) ? x1[r].x : (t == 1) ? x1[r].y : (t == 2) ? x1[r].z : x1[r].w;
            float xv1 = (t == 0) ? x2[r].x : (t == 1) ? x2[r].y : (t == 2) ? x2[r].z : x2[r].w;
            float xv2 = (t == 0) ? x3[r].x : (t == 1) ? x3[r].y : (t == 2) ? x3[r].z : x3[r].w;
            aA[r][j]    = fmaf(xsv, w.x, aA[r][j]);
            aC[r][j]    = fmaf(xsv, w.y, aC[r][j]);
            aB[r][0][j] = fmaf(xv0, w.z, aB[r][0][j]);
            aB[r][1][j] = fmaf(xv1, w.z, aB[r][1][j]);
            aB[r][2][j] = fmaf(xv2, w.z, aB[r][2][j]);
            aP[r][0][j] = fmaf(xv0, w.w, aP[r][0][j]);
            aP[r][1][j] = fmaf(xv1, w.w, aP[r][1][j]);
            aP[r][2][j] = fmaf(xv2, w.w, aP[r][2][j]);
          }
        }
      }
    }
    uint4* dst = y ? rec_j4 : rec_i4;
    #pragma unroll
    for (int r = 0; r < 2; ++r) {
      int node = nb + ng + 16 * r;
      if (node < N) {
        #pragma unroll
        for (int j = 0; j < 4; ++j) {
          int c = 16 * j + cg;
          uint4 o;
          o.x = pk(aA[r][j], aC[r][j]);
          o.y = pk(aB[r][0][j], aB[r][1][j]);
          o.z = pk(aB[r][2][j], aP[r][0][j]);
          o.w = pk(aP[r][1][j], aP[r][2][j]);
          dst[(size_t)node * 64 + c] = o;
        }
      }
    }
  }
}

// Fused hot kernel: one wave per node, wave-uniform scalar edge metadata,
// 2-edge unrolled loop with double prefetch, in-wave epilogue matvecs.
// (r3-proven scalar edge math + exp2f-hoisted tanh args, no min clamps.)
__global__ __launch_bounds__(512) void k_edges(
    const u16* __restrict__ rec_i, const u16* __restrict__ rec_j,
    const float4* __restrict__ erecA, const int* __restrict__ erecI,
    const int* __restrict__ rowptr,
    const float* __restrict__ scalar, const float* __restrict__ vector,
    const float* __restrict__ bss, const float* __restrict__ bvs,
    const float* __restrict__ bsv, const float* __restrict__ bsl,
    const u32* __restrict__ Wsl2g, const u32* __restrict__ Wpkg,
    const float* __restrict__ bcg,
    float* __restrict__ out_s, float* __restrict__ out_v, int N) {
  __shared__ u32 sWsl[4096];        // 16 KB
  __shared__ u32 sWv[2048];         // 8 KB  (Wvl_right only)
  __shared__ float sStage[8 * 128]; // 4 KB, wave-private epilogue stage
  int tid = threadIdx.x, lane = tid & 63, wv = tid >> 6;
  for (int o = tid; o < 4096; o += 512) sWsl[o] = Wsl2g[o];
  for (int o = tid; o < 2048; o += 512) sWv[o] = Wpkg[o];
  __syncthreads();   // the only block barrier

  int node = __builtin_amdgcn_readfirstlane((int)(blockIdx.x * 8) + wv);
  if (node >= N) node = N - 1;

  uint4 riv = *(const uint4*)(rec_i + ((size_t)node << 9) + lane * 8);
  float aiB  = lo16(riv.x) + bss[lane];
  float KciB = TWOL2E * (hi16(riv.x) + bsv[lane]);
  float Bvs  = bvs[lane];
  float bib0 = lo16(riv.y) + Bvs;
  float bib1 = hi16(riv.y) + Bvs;
  float bib2 = lo16(riv.z) + Bvs;
  float Pi0  = hi16(riv.z), Pi1 = lo16(riv.w), Pi2 = hi16(riv.w);
  float bsl_c = bsl[lane], bc_c = bcg[lane];

  float us = 0, uv = 0, t0 = 0, t1 = 0, t2 = 0, g0 = 0, g1 = 0, g2 = 0, wa = 0;
  int rp = rowptr[node], re = rowptr[node + 1];
  u32 lane16 = (u32)lane << 4;
  const char* rjb = (const char*)rec_j;

  // erecI has 64 zeroed ints of slack past E -> prefetch reads always valid
  u32 ra = (u32)erecI[rp];
  u32 rb = (u32)erecI[rp + 1];
  uint4 pre0 = *(const uint4*)(rjb + ((ra << 10) + lane16));
  uint4 pre1 = *(const uint4*)(rjb + ((rb << 10) + lane16));
  int p = rp;
  #define EDGE_MATH(CUR, EV)                                                  \
    {                                                                         \
      float nrm = EV.x, dx = EV.y, dy = EV.z, dz = EV.w;                      \
      float aj  = lo16(CUR.x), cj  = hi16(CUR.x);                             \
      float bj0 = lo16(CUR.y), bj1 = hi16(CUR.y), bj2 = lo16(CUR.z);          \
      float rj0 = hi16(CUR.z), rj1 = lo16(CUR.w), rj2 = hi16(CUR.w);          \
      float xs  = aiB + aj;                                                   \
      float s2s = xs * frcp(1.f + exp2f(xs * NL2E));                          \
      float yv  = (bib0 + bj0) * dx;                                          \
      yv = fmaf(bib1 + bj1, dy, yv);                                          \
      yv = fmaf(bib2 + bj2, dz, yv);                                          \
      float v2s = yv * frcp(1.f + exp2f(yv * NL2E));                          \
      float qh  = fmaf(TWOL2E, cj, KciB);                                     \
      float th0 = fmaf(-2.f, frcp(1.f + exp2f(qh * dx)), 1.f);                \
      float th1 = fmaf(-2.f, frcp(1.f + exp2f(qh * dy)), 1.f);                \
      float th2 = fmaf(-2.f, frcp(1.f + exp2f(qh * dz)), 1.f);                \
      us = fmaf(nrm, s2s, us); uv = fmaf(nrm, v2s, uv);                       \
      t0 = fmaf(nrm, th0, t0); t1 = fmaf(nrm, th1, t1); t2 = fmaf(nrm, th2, t2);\
      g0 = fmaf(nrm, rj0, g0); g1 = fmaf(nrm, rj1, g1); g2 = fmaf(nrm, rj2, g2);\
      wa += nrm;                                                              \
    }
  for (; p + 1 < re; p += 2) {
    uint4 cur0 = pre0, cur1 = pre1;
    u32 rn0 = (u32)erecI[p + 2];
    u32 rn1 = (u32)erecI[p + 3];
    pre0 = *(const uint4*)(rjb + ((rn0 << 10) + lane16));
    pre1 = *(const uint4*)(rjb + ((rn1 << 10) + lane16));
    float4 e0 = erecA[p];
    float4 e1 = erecA[p + 1];
    EDGE_MATH(cur0, e0)
    EDGE_MATH(cur1, e1)
  }
  if (p < re) {
    uint4 cur0 = pre0;
    float4 e0 = erecA[p];
    EDGE_MATH(cur0, e0)
  }
  #undef EDGE_MATH

  // ---- epilogue: scalar head (wave-local, no block barrier) ----
  float* mys = &sStage[wv * 128];
  mys[lane] = us; mys[64 + lane] = uv;
  __threadfence_block();
  float acc = wa * bsl_c;
  #pragma unroll
  for (int g = 0; g < 32; ++g) {
    float4 u = *(const float4*)&mys[4 * g];
    uint2 w = *(const uint2*)&sWsl[(g * 64 + lane) * 2];
    acc = fmaf(u.x, lo16(w.x), acc);
    acc = fmaf(u.y, hi16(w.x), acc);
    acc = fmaf(u.z, lo16(w.y), acc);
    acc = fmaf(u.w, hi16(w.y), acc);
  }
  size_t so = ((size_t)node << 6) + lane;
  out_s[so] = acc * frcp(1.f + exp2f(acc * NL2E)) + scalar[so];

  // ---- epilogue: vector head (t-part matvec only; x,y parts precomputed) ----
  float gg[3] = {g0, g1, g2}, tt[3] = {t0, t1, t2}, Pi[3] = {Pi0, Pi1, Pi2};
  #pragma unroll
  for (int d = 0; d < 3; ++d) {
    size_t vo = (((size_t)node * 3 + d) << 6) + lane;
    float vid = vector[vo];
    __threadfence_block();
    mys[lane] = tt[d];
    __threadfence_block();
    float a2 = fmaf(wa, bc_c + Pi[d], gg[d]);
    #pragma unroll
    for (int g = 0; g < 16; ++g) {
      float4 tu = *(const float4*)&mys[4 * g];
      uint2 w = *(const uint2*)&sWv[(g * 64 + lane) * 2];
      a2 = fmaf(tu.x, lo16(w.x), a2); a2 = fmaf(tu.y, hi16(w.x), a2);
      a2 = fmaf(tu.z, lo16(w.y), a2); a2 = fmaf(tu.w, hi16(w.y), a2);
    }
    float th = fmaf(-2.f, frcp(1.f + exp2f(TWOL2E * a2)), 1.f);
    out_v[vo] = th + vid;
  }
}

extern "C" void kernel_launch(void* const* d_in, const int* in_sizes, int n_in,
                              void* d_out, int out_size, void* d_ws, size_t ws_size,
                              hipStream_t stream) {
  const float* scalar   = (const float*)d_in[0];
  const float* vector   = (const float*)d_in[1];
  const float* position = (const float*)d_in[2];
  const int*   eidx     = (const int*)d_in[3];
  const float* attr     = (const float*)d_in[4];
  const float* Wss = (const float*)d_in[5];
  const float* bss = (const float*)d_in[6];
  const float* Wvs = (const float*)d_in[7];
  const float* bvs = (const float*)d_in[8];
  const float* Wsl = (const float*)d_in[9];
  const float* bsl = (const float*)d_in[10];
  const float* Wsv = (const float*)d_in[11];
  const float* bsv = (const float*)d_in[12];
  const float* Wvv = (const float*)d_in[13];
  const float* bvv = (const float*)d_in[14];
  const float* Wvl = (const float*)d_in[15];
  const float* bvl = (const float*)d_in[16];

  int N = in_sizes[0] / 64;
  int E = in_sizes[4];
  int NB = (N + 255) / 256;   // scan blocks (must be <= 1024)

  char* wsb = (char*)d_ws;
  size_t off = 0;
  auto alloc = [&](size_t bytes) -> char* {
    char* p = wsb + off;
    off += (bytes + 255) & ~(size_t)255;
    return p;
  };
  float*  deg    = (float*)alloc((size_t)N * 4);
  int*    cnt    = (int*)alloc((size_t)N * 4);
  int*    rowptr = (int*)alloc((size_t)(N + 1) * 4);
  int*    cursor = (int*)alloc((size_t)N * 4);
  int*    blocksum = (int*)alloc((size_t)NB * 4);
  int*    blockoff = (int*)alloc((size_t)NB * 4);
  float4* erecA  = (float4*)alloc((size_t)E * 16);
  int*    erecI  = (int*)alloc((size_t)(E + 64) * 4);   // +slack for prefetch reads
  u16*    rec_i  = (u16*)alloc((size_t)N * 512 * 2);
  u16*    rec_j  = (u16*)alloc((size_t)N * 512 * 2);
  float*  WTall  = (float*)alloc(2 * 64 * 64 * 4 * 4);  // 128 KB interleaved weights
  u32*    Wsl2   = (u32*)alloc(4096 * 4);
  u32*    Wpk    = (u32*)alloc(2048 * 4);
  float*  WcTmp  = (float*)alloc(64 * 128 * 4);
  float*  bc     = (float*)alloc(64 * 4);
  int*    flag   = (int*)alloc(4);
  (void)ws_size; (void)n_in; (void)out_size;

  // zero deg + cnt (contiguous region) and the erecI prefetch slack
  hipMemsetAsync(deg, 0, (size_t)((char*)rowptr - (char*)deg), stream);
  hipMemsetAsync(erecI + E, 0, 64 * 4, stream);

  k_prep1<<<34, 256, 0, stream>>>(Wvl, Wvv, bvv, bvl, eidx, E, flag, WcTmp, bc);
  k_prep2<<<11, 256, 0, stream>>>(Wss, Wsv, Wvs, Wsl, Wvl, WcTmp, Wsl2, Wpk, WTall);
  k_deg<<<(E + 255) / 256, 256, 0, stream>>>(eidx, flag, attr, deg, cnt, E);
  k_scan_red<<<NB, 256, 0, stream>>>(cnt, blocksum, N);
  k_scan_mid<<<1, 1024, 0, stream>>>(blocksum, blockoff, NB, rowptr, N, E);
  k_scan_out<<<NB, 256, 0, stream>>>(cnt, blockoff, rowptr, cursor, N);
  k_fill<<<(E + 255) / 256, 256, 0, stream>>>(eidx, flag, attr, deg, position, cursor, erecA, erecI, E);
  k_gemm_rec<<<(N + 31) / 32, 256, 0, stream>>>(scalar, vector, WTall,
                                                (uint4*)rec_i, (uint4*)rec_j, N);
  k_edges<<<(N + 7) / 8, 512, 0, stream>>>(rec_i, rec_j, erecA, erecI, rowptr,
                                           scalar, vector, bss, bvs, bsv, bsl,
                                           Wsl2, Wpk, bc,
                                           (float*)d_out, (float*)d_out + (size_t)N * 64, N);
}

// Round 6
// 565.826 us; speedup vs baseline: 1.0860x; 1.0860x over previous
//
#include <hip/hip_runtime.h>
#include <cstdint>
#include <cstddef>

typedef unsigned int   u32;
typedef unsigned short u16;

__device__ __forceinline__ float bf2f(u32 bits16) { return __uint_as_float(bits16 << 16); }
__device__ __forceinline__ u16 f2bf(float f) {
  u32 u = __float_as_uint(f);
  u = u + 0x7FFFu + ((u >> 16) & 1u);   // round-to-nearest-even
  return (u16)(u >> 16);
}
__device__ __forceinline__ u32 pk(float a, float b) {
  return (u32)f2bf(a) | ((u32)f2bf(b) << 16);
}
__device__ __forceinline__ float lo16(u32 w) { return bf2f(w & 0xFFFFu); }
__device__ __forceinline__ float hi16(u32 w) { return bf2f(w >> 16); }
__device__ __forceinline__ float frcp(float x) { return __builtin_amdgcn_rcpf(x); }

#define NL2E   (-1.4426950408889634f)
#define TWOL2E (2.8853900817779268f)
#define CNTSC  1073741824.0            // 2^30: cnt encoded above deg in one double

__device__ __forceinline__ int load_idx(const int* eidx, int is64, long long pos) {
  if (is64) return (int)(((const long long*)eidx)[pos]);
  return eidx[pos];
}

// ---- prep stage 1 (grid 34): WcTmp = Wvl_left @ Wvv, edge-width detect, bc ----
__global__ void k_prep1(const float* Wvl, const float* Wvv,
                        const float* bvv, const float* bvl,
                        const int* eidx, int E, int* flag,
                        float* WcTmp, float* bc) {
  int b = blockIdx.x, tid = threadIdx.x;
  if (b < 32) {
    int c = 2 * b + (tid >> 7), kk = tid & 127;
    float s = 0.f;
    for (int m = 0; m < 64; ++m) s += Wvl[c * 128 + m] * Wvv[m * 128 + kk];
    WcTmp[c * 128 + kk] = s;
  } else if (b == 32) {
    __shared__ int zc;
    if (tid == 0) zc = 0;
    __syncthreads();
    int n = (E < 1024) ? E : 1024;
    int local = 0;
    for (int i = tid; i < n; i += 256) {
      if (eidx[2 * i + 1] == 0) local++;   // high words if int64 (all 0)
    }
    atomicAdd(&zc, local);
    __syncthreads();
    if (tid == 0) *flag = (zc >= (n >> 1)) ? 1 : 0;
  } else if (b == 33) {
    if (tid < 64) {
      float s = 0.f;
      for (int m = 0; m < 64; ++m) s += Wvl[tid * 128 + m] * bvv[m];
      bc[tid] = s + bvl[tid];
    }
  }
}

// ---- prep stage 2 (grid 11): bf16 epilogue tables + interleaved GEMM weight table ----
// Wsl2[(g*64+c)*2+h] = pack(Wsl[c][4g+2h], Wsl[c][4g+2h+1]), g<32
// Wpk : 2048 u32 : Wvl_right packed, same (g,c,h) layout, g<16
// WTall[((y*64+k)*64+c)*4+m]: m0=Wss[c][64y+k] m1=Wsv[..] m2=Wvs[..] m3=WcTmp[..]
__global__ void k_prep2(const float* Wss, const float* Wsv, const float* Wvs,
                        const float* Wsl, const float* Wvl, const float* WcTmp,
                        u32* Wsl2, u32* Wpk, float* WTall) {
  int b = blockIdx.x, tid = threadIdx.x;
  if (b < 2) {
    for (int i = 0; i < 8; ++i) {
      int o = b * 2048 + i * 256 + tid;
      int h = o & 1, c = (o >> 1) & 63, g = o >> 7;
      int k = 4 * g + 2 * h;
      Wsl2[o] = pk(Wsl[c * 128 + k], Wsl[c * 128 + k + 1]);
    }
  } else if (b == 2) {
    for (int i = 0; i < 8; ++i) {
      int o = i * 256 + tid;
      int h = o & 1, c = (o >> 1) & 63, g = o >> 7;
      int k = 4 * g + 2 * h;
      Wpk[o] = pk(Wvl[c * 128 + 64 + k], Wvl[c * 128 + 64 + k + 1]);
    }
  } else {
    for (int i = 0; i < 16; ++i) {
      int o = (b - 3) * 4096 + i * 256 + tid;
      int m = o & 3, c = (o >> 2) & 63, k = (o >> 8) & 63, y = o >> 14;
      int src = c * 128 + 64 * y + k;
      float v;
      if (m == 0)      v = Wss[src];
      else if (m == 1) v = Wsv[src];
      else if (m == 2) v = Wvs[src];
      else             v = WcTmp[src];
      WTall[o] = v;
    }
  }
}

// one fp64 atomic per edge: dpk[col] += attr + 2^30  (cnt in high part, deg in low)
__global__ void k_deg(const int* eidx, const int* flag, const float* attr,
                      double* dpk, int E) {
  int e = blockIdx.x * 256 + threadIdx.x;
  if (e >= E) return;
  int is64 = *flag;
  int col = load_idx(eidx, is64, (long long)E + e);
  atomicAdd(&dpk[col], (double)attr[e] + CNTSC);
}

// ---- multi-block exclusive scan of cnt -> rowptr, cursor ----
__global__ void k_scan_red(const double* dpk, int* blocksum, int N) {
  __shared__ int lds[256];
  int tid = threadIdx.x, idx = blockIdx.x * 256 + tid;
  lds[tid] = (idx < N) ? (int)(dpk[idx] * (1.0 / CNTSC)) : 0;
  __syncthreads();
  for (int off = 128; off > 0; off >>= 1) {
    if (tid < off) lds[tid] += lds[tid + off];
    __syncthreads();
  }
  if (tid == 0) blocksum[blockIdx.x] = lds[0];
}

__global__ void k_scan_mid(const int* blocksum, int* blockoff, int NB, int* rowptr, int N, int E) {
  __shared__ int lds[1024];
  int tid = threadIdx.x;
  int v = (tid < NB) ? blocksum[tid] : 0;
  lds[tid] = v;
  __syncthreads();
  for (int off = 1; off < 1024; off <<= 1) {
    int t = (tid >= off) ? lds[tid - off] : 0;
    __syncthreads();
    lds[tid] += t;
    __syncthreads();
  }
  if (tid < NB) blockoff[tid] = lds[tid] - v;   // exclusive
  if (tid == 0) rowptr[N] = E;
}

__global__ void k_scan_out(const double* dpk, const int* blockoff, int* rowptr, int* cursor, int N) {
  __shared__ int lds[256];
  int tid = threadIdx.x, idx = blockIdx.x * 256 + tid;
  int v = (idx < N) ? (int)(dpk[idx] * (1.0 / CNTSC)) : 0;
  lds[tid] = v;
  __syncthreads();
  for (int off = 1; off < 256; off <<= 1) {
    int t = (tid >= off) ? lds[tid - off] : 0;
    __syncthreads();
    lds[tid] += t;
    __syncthreads();
  }
  if (idx < N) {
    int o = blockoff[blockIdx.x] + lds[tid] - v;
    rowptr[idx] = o;
    cursor[idx] = o;
  }
}

// CSR fill: erecA[p]={norm, dx, dy, dz} (d = pos_i - pos_j), erecI[p]=row
__global__ void k_fill(const int* eidx, const int* flag, const float* attr, const double* dpk,
                       const float* pos, int* cursor, float4* erecA, int* erecI, int E) {
  int e = blockIdx.x * 256 + threadIdx.x;
  if (e >= E) return;
  int is64 = *flag;
  int r  = load_idx(eidx, is64, e);
  int cl = load_idx(eidx, is64, (long long)E + e);
  double pr = dpk[r], pc = dpk[cl];
  double crd = (double)(int)(pr * (1.0 / CNTSC));
  double ccd = (double)(int)(pc * (1.0 / CNTSC));
  float dr = (float)(pr - crd * CNTSC);
  float dc = (float)(pc - ccd * CNTSC);
  float disr = (dr > 0.f) ? rsqrtf(dr) : 0.f;
  float disc = (dc > 0.f) ? rsqrtf(dc) : 0.f;
  float nrm = disr * disc * attr[e];
  float dx = pos[cl * 3 + 0] - pos[r * 3 + 0];
  float dy = pos[cl * 3 + 1] - pos[r * 3 + 1];
  float dz = pos[cl * 3 + 2] - pos[r * 3 + 2];
  int p = atomicAdd(&cursor[cl], 1);
  erecA[p] = make_float4(nrm, dx, dy, dz);
  erecI[p] = r;
}

// Fused node GEMM v6: 512 threads, 32 nodes/block, 1 node x 4 channels per thread
// -> 32 live accumulators per y-phase. X staged once (32KB, XOR-swizzled cols:
// col = k ^ ((n&7)<<2) keeps the unpadded [64] stride conflict-free). W staged
// in 32KB k-half chunks (8 barriers total). LDS = 64KB -> 2 blocks/CU = 4 waves/SIMD.
#define PROC(xsv, xv0, xv1, xv2, kk)                                          \
  { _Pragma("unroll")                                                         \
    for (int j = 0; j < 4; ++j) {                                             \
      float4 w = Wch[(kk) * 64 + 16 * j + cg];                                \
      aA[j]  = fmaf(xsv, w.x, aA[j]);  aC[j]  = fmaf(xsv, w.y, aC[j]);        \
      aB0[j] = fmaf(xv0, w.z, aB0[j]); aB1[j] = fmaf(xv1, w.z, aB1[j]);       \
      aB2[j] = fmaf(xv2, w.z, aB2[j]);                                        \
      aP0[j] = fmaf(xv0, w.w, aP0[j]); aP1[j] = fmaf(xv1, w.w, aP1[j]);       \
      aP2[j] = fmaf(xv2, w.w, aP2[j]); } }

__global__ __launch_bounds__(512, 2) void k_gemm_rec(
    const float* __restrict__ scalar, const float* __restrict__ vector,
    const float* __restrict__ WTall,
    uint4* __restrict__ rec_i4, uint4* __restrict__ rec_j4, int N) {
  __shared__ float Xs[4][32][64];   // 32 KB, swizzled k-columns
  __shared__ float4 Wch[2048];      // 32 KB, one 32-k chunk
  int tid = threadIdx.x;
  int nb = blockIdx.x * 32;
  {
    int n = tid >> 4, kq = tid & 15;
    float4 v = make_float4(0.f, 0.f, 0.f, 0.f);
    if (nb + n < N) v = *(const float4*)(scalar + (size_t)(nb + n) * 64 + 4 * kq);
    *(float4*)&Xs[0][n][(4 * kq) ^ ((n & 7) << 2)] = v;
  }
  #pragma unroll
  for (int i = 0; i < 3; ++i) {
    int q = tid + i * 512;
    int r = q >> 4, kq = q & 15;
    int n = r / 3, d = r - n * 3;
    float4 v = make_float4(0.f, 0.f, 0.f, 0.f);
    if (nb + n < N) v = *(const float4*)(vector + (size_t)(nb + n) * 192 + d * 64 + 4 * kq);
    *(float4*)&Xs[1 + d][n][(4 * kq) ^ ((n & 7) << 2)] = v;
  }
  int cg = tid & 15, nl = tid >> 4;
  int xsw = (nl & 7) << 2;
  int node = nb + nl;
  #pragma unroll
  for (int y = 0; y < 2; ++y) {
    float aA[4] = {}, aC[4] = {}, aB0[4] = {}, aB1[4] = {}, aB2[4] = {};
    float aP0[4] = {}, aP1[4] = {}, aP2[4] = {};
    const float4* Wg = (const float4*)WTall + (size_t)y * 4096;
    #pragma unroll
    for (int kh = 0; kh < 2; ++kh) {
      __syncthreads();   // Wch free to overwrite (also covers X staging, 1st iter)
      #pragma unroll
      for (int i = 0; i < 4; ++i) Wch[i * 512 + tid] = Wg[kh * 2048 + i * 512 + tid];
      __syncthreads();
      #pragma unroll 2
      for (int k4 = 0; k4 < 32; k4 += 4) {
        int col = ((kh << 5) + k4) ^ xsw;
        float4 x0 = *(const float4*)&Xs[0][nl][col];
        float4 x1 = *(const float4*)&Xs[1][nl][col];
        float4 x2 = *(const float4*)&Xs[2][nl][col];
        float4 x3 = *(const float4*)&Xs[3][nl][col];
        PROC(x0.x, x1.x, x2.x, x3.x, k4 + 0)
        PROC(x0.y, x1.y, x2.y, x3.y, k4 + 1)
        PROC(x0.z, x1.z, x2.z, x3.z, k4 + 2)
        PROC(x0.w, x1.w, x2.w, x3.w, k4 + 3)
      }
    }
    if (node < N) {
      uint4* dst = y ? rec_j4 : rec_i4;
      #pragma unroll
      for (int j = 0; j < 4; ++j) {
        uint4 o;
        o.x = pk(aA[j], aC[j]);
        o.y = pk(aB0[j], aB1[j]);
        o.z = pk(aB2[j], aP0[j]);
        o.w = pk(aP1[j], aP2[j]);
        dst[(size_t)node * 64 + 16 * j + cg] = o;
      }
    }
  }
}
#undef PROC

// Fused hot kernel: one wave per node, 4-edge unrolled loop with 4-deep prefetch
// (rec_j gathers are HBM-latency bound), in-wave epilogue matvecs.
__global__ __launch_bounds__(512) void k_edges(
    const u16* __restrict__ rec_i, const u16* __restrict__ rec_j,
    const float4* __restrict__ erecA, const int* __restrict__ erecI,
    const int* __restrict__ rowptr,
    const float* __restrict__ scalar, const float* __restrict__ vector,
    const float* __restrict__ bss, const float* __restrict__ bvs,
    const float* __restrict__ bsv, const float* __restrict__ bsl,
    const u32* __restrict__ Wsl2g, const u32* __restrict__ Wpkg,
    const float* __restrict__ bcg,
    float* __restrict__ out_s, float* __restrict__ out_v, int N) {
  __shared__ u32 sWsl[4096];        // 16 KB
  __shared__ u32 sWv[2048];         // 8 KB  (Wvl_right only)
  __shared__ float sStage[8 * 128]; // 4 KB, wave-private epilogue stage
  int tid = threadIdx.x, lane = tid & 63, wv = tid >> 6;
  for (int o = tid; o < 4096; o += 512) sWsl[o] = Wsl2g[o];
  for (int o = tid; o < 2048; o += 512) sWv[o] = Wpkg[o];
  __syncthreads();   // the only block barrier

  int node = __builtin_amdgcn_readfirstlane((int)(blockIdx.x * 8) + wv);
  if (node >= N) node = N - 1;

  uint4 riv = *(const uint4*)(rec_i + ((size_t)node << 9) + lane * 8);
  float aiB  = lo16(riv.x) + bss[lane];
  float KciB = TWOL2E * (hi16(riv.x) + bsv[lane]);
  float Bvs  = bvs[lane];
  float bib0 = lo16(riv.y) + Bvs;
  float bib1 = hi16(riv.y) + Bvs;
  float bib2 = lo16(riv.z) + Bvs;
  float Pi0  = hi16(riv.z), Pi1 = lo16(riv.w), Pi2 = hi16(riv.w);
  float bsl_c = bsl[lane], bc_c = bcg[lane];

  float us = 0, uv = 0, t0 = 0, t1 = 0, t2 = 0, g0 = 0, g1 = 0, g2 = 0, wa = 0;
  int rp = rowptr[node], re = rowptr[node + 1];
  u32 lane16 = (u32)lane << 4;
  const char* rjb = (const char*)rec_j;

  // erecI has 64 zeroed ints of slack past E -> prefetch reads always valid
  u32 i0 = (u32)erecI[rp],     i1 = (u32)erecI[rp + 1];
  u32 i2 = (u32)erecI[rp + 2], i3 = (u32)erecI[rp + 3];
  uint4 pr0 = *(const uint4*)(rjb + ((i0 << 10) + lane16));
  uint4 pr1 = *(const uint4*)(rjb + ((i1 << 10) + lane16));
  uint4 pr2 = *(const uint4*)(rjb + ((i2 << 10) + lane16));
  uint4 pr3 = *(const uint4*)(rjb + ((i3 << 10) + lane16));
  int p = rp;
  #define EDGE_MATH(CUR, EV)                                                  \
    {                                                                         \
      float nrm = EV.x, dx = EV.y, dy = EV.z, dz = EV.w;                      \
      float aj  = lo16(CUR.x), cj  = hi16(CUR.x);                             \
      float bj0 = lo16(CUR.y), bj1 = hi16(CUR.y), bj2 = lo16(CUR.z);          \
      float rj0 = hi16(CUR.z), rj1 = lo16(CUR.w), rj2 = hi16(CUR.w);          \
      float xs  = aiB + aj;                                                   \
      float s2s = xs * frcp(1.f + exp2f(xs * NL2E));                          \
      float yv  = (bib0 + bj0) * dx;                                          \
      yv = fmaf(bib1 + bj1, dy, yv);                                          \
      yv = fmaf(bib2 + bj2, dz, yv);                                          \
      float v2s = yv * frcp(1.f + exp2f(yv * NL2E));                          \
      float qh  = fmaf(TWOL2E, cj, KciB);                                     \
      float th0 = fmaf(-2.f, frcp(1.f + exp2f(qh * dx)), 1.f);                \
      float th1 = fmaf(-2.f, frcp(1.f + exp2f(qh * dy)), 1.f);                \
      float th2 = fmaf(-2.f, frcp(1.f + exp2f(qh * dz)), 1.f);                \
      us = fmaf(nrm, s2s, us); uv = fmaf(nrm, v2s, uv);                       \
      t0 = fmaf(nrm, th0, t0); t1 = fmaf(nrm, th1, t1); t2 = fmaf(nrm, th2, t2);\
      g0 = fmaf(nrm, rj0, g0); g1 = fmaf(nrm, rj1, g1); g2 = fmaf(nrm, rj2, g2);\
      wa += nrm;                                                              \
    }
  for (; p + 3 < re; p += 4) {
    uint4 c0 = pr0, c1 = pr1, c2 = pr2, c3 = pr3;
    u32 n0 = (u32)erecI[p + 4], n1 = (u32)erecI[p + 5];
    u32 n2 = (u32)erecI[p + 6], n3 = (u32)erecI[p + 7];
    pr0 = *(const uint4*)(rjb + ((n0 << 10) + lane16));
    pr1 = *(const uint4*)(rjb + ((n1 << 10) + lane16));
    pr2 = *(const uint4*)(rjb + ((n2 << 10) + lane16));
    pr3 = *(const uint4*)(rjb + ((n3 << 10) + lane16));
    float4 e0 = erecA[p],     e1 = erecA[p + 1];
    float4 e2 = erecA[p + 2], e3 = erecA[p + 3];
    EDGE_MATH(c0, e0)
    EDGE_MATH(c1, e1)
    EDGE_MATH(c2, e2)
    EDGE_MATH(c3, e3)
  }
  if (p < re)     { float4 e = erecA[p];     EDGE_MATH(pr0, e) }
  if (p + 1 < re) { float4 e = erecA[p + 1]; EDGE_MATH(pr1, e) }
  if (p + 2 < re) { float4 e = erecA[p + 2]; EDGE_MATH(pr2, e) }
  #undef EDGE_MATH

  // ---- epilogue: scalar head (wave-local, no block barrier) ----
  float* mys = &sStage[wv * 128];
  mys[lane] = us; mys[64 + lane] = uv;
  __threadfence_block();
  float acc = wa * bsl_c;
  #pragma unroll
  for (int g = 0; g < 32; ++g) {
    float4 u = *(const float4*)&mys[4 * g];
    uint2 w = *(const uint2*)&sWsl[(g * 64 + lane) * 2];
    acc = fmaf(u.x, lo16(w.x), acc);
    acc = fmaf(u.y, hi16(w.x), acc);
    acc = fmaf(u.z, lo16(w.y), acc);
    acc = fmaf(u.w, hi16(w.y), acc);
  }
  size_t so = ((size_t)node << 6) + lane;
  out_s[so] = acc * frcp(1.f + exp2f(acc * NL2E)) + scalar[so];

  // ---- epilogue: vector head (t-part matvec only; x,y parts precomputed) ----
  float gg[3] = {g0, g1, g2}, tt[3] = {t0, t1, t2}, Pi[3] = {Pi0, Pi1, Pi2};
  #pragma unroll
  for (int d = 0; d < 3; ++d) {
    size_t vo = (((size_t)node * 3 + d) << 6) + lane;
    float vid = vector[vo];
    __threadfence_block();
    mys[lane] = tt[d];
    __threadfence_block();
    float a2 = fmaf(wa, bc_c + Pi[d], gg[d]);
    #pragma unroll
    for (int g = 0; g < 16; ++g) {
      float4 tu = *(const float4*)&mys[4 * g];
      uint2 w = *(const uint2*)&sWv[(g * 64 + lane) * 2];
      a2 = fmaf(tu.x, lo16(w.x), a2); a2 = fmaf(tu.y, hi16(w.x), a2);
      a2 = fmaf(tu.z, lo16(w.y), a2); a2 = fmaf(tu.w, hi16(w.y), a2);
    }
    float th = fmaf(-2.f, frcp(1.f + exp2f(TWOL2E * a2)), 1.f);
    out_v[vo] = th + vid;
  }
}

extern "C" void kernel_launch(void* const* d_in, const int* in_sizes, int n_in,
                              void* d_out, int out_size, void* d_ws, size_t ws_size,
                              hipStream_t stream) {
  const float* scalar   = (const float*)d_in[0];
  const float* vector   = (const float*)d_in[1];
  const float* position = (const float*)d_in[2];
  const int*   eidx     = (const int*)d_in[3];
  const float* attr     = (const float*)d_in[4];
  const float* Wss = (const float*)d_in[5];
  const float* bss = (const float*)d_in[6];
  const float* Wvs = (const float*)d_in[7];
  const float* bvs = (const float*)d_in[8];
  const float* Wsl = (const float*)d_in[9];
  const float* bsl = (const float*)d_in[10];
  const float* Wsv = (const float*)d_in[11];
  const float* bsv = (const float*)d_in[12];
  const float* Wvv = (const float*)d_in[13];
  const float* bvv = (const float*)d_in[14];
  const float* Wvl = (const float*)d_in[15];
  const float* bvl = (const float*)d_in[16];

  int N = in_sizes[0] / 64;
  int E = in_sizes[4];
  int NB = (N + 255) / 256;   // scan blocks (must be <= 1024)

  char* wsb = (char*)d_ws;
  size_t off = 0;
  auto alloc = [&](size_t bytes) -> char* {
    char* p = wsb + off;
    off += (bytes + 255) & ~(size_t)255;
    return p;
  };
  double* dpk    = (double*)alloc((size_t)N * 8);
  int*    rowptr = (int*)alloc((size_t)(N + 1) * 4);
  int*    cursor = (int*)alloc((size_t)N * 4);
  int*    blocksum = (int*)alloc((size_t)NB * 4);
  int*    blockoff = (int*)alloc((size_t)NB * 4);
  float4* erecA  = (float4*)alloc((size_t)E * 16);
  int*    erecI  = (int*)alloc((size_t)(E + 64) * 4);   // +slack for prefetch reads
  u16*    rec_i  = (u16*)alloc((size_t)N * 512 * 2);
  u16*    rec_j  = (u16*)alloc((size_t)N * 512 * 2);
  float*  WTall  = (float*)alloc(2 * 64 * 64 * 4 * 4);  // 128 KB interleaved weights
  u32*    Wsl2   = (u32*)alloc(4096 * 4);
  u32*    Wpk    = (u32*)alloc(2048 * 4);
  float*  WcTmp  = (float*)alloc(64 * 128 * 4);
  float*  bc     = (float*)alloc(64 * 4);
  int*    flag   = (int*)alloc(4);
  (void)ws_size; (void)n_in; (void)out_size;

  // zero dpk and the erecI prefetch slack
  hipMemsetAsync(dpk, 0, (size_t)((char*)rowptr - (char*)dpk), stream);
  hipMemsetAsync(erecI + E, 0, 64 * 4, stream);

  k_prep1<<<34, 256, 0, stream>>>(Wvl, Wvv, bvv, bvl, eidx, E, flag, WcTmp, bc);
  k_prep2<<<11, 256, 0, stream>>>(Wss, Wsv, Wvs, Wsl, Wvl, WcTmp, Wsl2, Wpk, WTall);
  k_deg<<<(E + 255) / 256, 256, 0, stream>>>(eidx, flag, attr, dpk, E);
  k_scan_red<<<NB, 256, 0, stream>>>(dpk, blocksum, N);
  k_scan_mid<<<1, 1024, 0, stream>>>(blocksum, blockoff, NB, rowptr, N, E);
  k_scan_out<<<NB, 256, 0, stream>>>(dpk, blockoff, rowptr, cursor, N);
  k_fill<<<(E + 255) / 256, 256, 0, stream>>>(eidx, flag, attr, dpk, position, cursor, erecA, erecI, E);
  k_gemm_rec<<<(N + 31) / 32, 512, 0, stream>>>(scalar, vector, WTall,
                                                (uint4*)rec_i, (uint4*)rec_j, N);
  k_edges<<<(N + 7) / 8, 512, 0, stream>>>(rec_i, rec_j, erecA, erecI, rowptr,
                                           scalar, vector, bss, bvs, bsv, bsl,
                                           Wsl2, Wpk, bc,
                                           (float*)d_out, (float*)d_out + (size_t)N * 64, N);
}

// Round 7
// 452.284 us; speedup vs baseline: 1.3586x; 1.2510x over previous
//
#include <hip/hip_runtime.h>
#include <cstdint>
#include <cstddef>

typedef unsigned int   u32;
typedef unsigned short u16;
typedef __attribute__((ext_vector_type(8))) short bf16x8;
typedef __attribute__((ext_vector_type(4))) float f32x4;

__device__ __forceinline__ float bf2f(u32 bits16) { return __uint_as_float(bits16 << 16); }
__device__ __forceinline__ u16 f2bf(float f) {
  u32 u = __float_as_uint(f);
  u = u + 0x7FFFu + ((u >> 16) & 1u);   // round-to-nearest-even
  return (u16)(u >> 16);
}
__device__ __forceinline__ u32 pk(float a, float b) {
  return (u32)f2bf(a) | ((u32)f2bf(b) << 16);
}
__device__ __forceinline__ float lo16(u32 w) { return bf2f(w & 0xFFFFu); }
__device__ __forceinline__ float hi16(u32 w) { return bf2f(w >> 16); }
__device__ __forceinline__ float frcp(float x) { return __builtin_amdgcn_rcpf(x); }

#define NL2E   (-1.4426950408889634f)
#define TWOL2E (2.8853900817779268f)
#define CNTSC  1073741824.0            // 2^30: cnt encoded above deg in one double

__device__ __forceinline__ int load_idx(const int* eidx, int is64, long long pos) {
  if (is64) return (int)(((const long long*)eidx)[pos]);
  return eidx[pos];
}

// ---- prep stage 1 (grid 34): WcTmp = Wvl_left @ Wvv, edge-width detect, bc ----
__global__ void k_prep1(const float* Wvl, const float* Wvv,
                        const float* bvv, const float* bvl,
                        const int* eidx, int E, int* flag,
                        float* WcTmp, float* bc) {
  int b = blockIdx.x, tid = threadIdx.x;
  if (b < 32) {
    int c = 2 * b + (tid >> 7), kk = tid & 127;
    float s = 0.f;
    for (int m = 0; m < 64; ++m) s += Wvl[c * 128 + m] * Wvv[m * 128 + kk];
    WcTmp[c * 128 + kk] = s;
  } else if (b == 32) {
    __shared__ int zc;
    if (tid == 0) zc = 0;
    __syncthreads();
    int n = (E < 1024) ? E : 1024;
    int local = 0;
    for (int i = tid; i < n; i += 256) {
      if (eidx[2 * i + 1] == 0) local++;   // high words if int64 (all 0)
    }
    atomicAdd(&zc, local);
    __syncthreads();
    if (tid == 0) *flag = (zc >= (n >> 1)) ? 1 : 0;
  } else if (b == 33) {
    if (tid < 64) {
      float s = 0.f;
      for (int m = 0; m < 64; ++m) s += Wvl[tid * 128 + m] * bvv[m];
      bc[tid] = s + bvl[tid];
    }
  }
}

// ---- prep stage 2 (grid 11) ----
// b0..1: Wsl2 bf16 table; b2: Wpk; b3..10: Wtg split-bf16 W^T for the MFMA GEMM.
// Wtg rows r (u16[512][128], hi at k, lo at 64+k):
//   r<256 (Gs cols): g=r>>6: 0 A_i=Wss_L, 1 C_i=Wsv_L, 2 A_j=Wss_R, 3 C_j=Wsv_R
//   r>=256 (Gv cols): g: 0 B_i=Wvs_L, 1 P_i=Wc_L, 2 B_j=Wvs_R, 3 P_j=Wc_R
__global__ void k_prep2(const float* Wss, const float* Wsv, const float* Wvs,
                        const float* Wsl, const float* Wvl, const float* WcTmp,
                        u32* Wsl2, u32* Wpk, u16* Wtg) {
  int b = blockIdx.x, tid = threadIdx.x;
  if (b < 2) {
    for (int i = 0; i < 8; ++i) {
      int o = b * 2048 + i * 256 + tid;
      int h = o & 1, c = (o >> 1) & 63, g = o >> 7;
      int k = 4 * g + 2 * h;
      Wsl2[o] = pk(Wsl[c * 128 + k], Wsl[c * 128 + k + 1]);
    }
  } else if (b == 2) {
    for (int i = 0; i < 8; ++i) {
      int o = i * 256 + tid;
      int h = o & 1, c = (o >> 1) & 63, g = o >> 7;
      int k = 4 * g + 2 * h;
      Wpk[o] = pk(Wvl[c * 128 + 64 + k], Wvl[c * 128 + 64 + k + 1]);
    }
  } else {
    for (int i = 0; i < 16; ++i) {
      int p = (b - 3) * 4096 + i * 256 + tid;   // 0..32767
      int r = p >> 6, k = p & 63;
      int g = (r >> 6) & 3, ch = r & 63;
      int src = ch * 128 + ((g & 2) ? 64 : 0) + k;
      float w;
      if (r < 256) w = (g & 1) ? Wsv[src] : Wss[src];
      else         w = (g & 1) ? WcTmp[src] : Wvs[src];
      u16 h = f2bf(w);
      Wtg[r * 128 + k] = h;
      Wtg[r * 128 + 64 + k] = f2bf(w - bf2f(h));
    }
  }
}

// one fp64 atomic per edge: dpk[col] += attr + 2^30  (cnt in high part, deg in low)
__global__ void k_deg(const int* eidx, const int* flag, const float* attr,
                      double* dpk, int E) {
  int e = blockIdx.x * 256 + threadIdx.x;
  if (e >= E) return;
  int is64 = *flag;
  int col = load_idx(eidx, is64, (long long)E + e);
  atomicAdd(&dpk[col], (double)attr[e] + CNTSC);
}

// ---- multi-block exclusive scan of cnt -> rowptr, cursor ----
__global__ void k_scan_red(const double* dpk, int* blocksum, int N) {
  __shared__ int lds[256];
  int tid = threadIdx.x, idx = blockIdx.x * 256 + tid;
  lds[tid] = (idx < N) ? (int)(dpk[idx] * (1.0 / CNTSC)) : 0;
  __syncthreads();
  for (int off = 128; off > 0; off >>= 1) {
    if (tid < off) lds[tid] += lds[tid + off];
    __syncthreads();
  }
  if (tid == 0) blocksum[blockIdx.x] = lds[0];
}

__global__ void k_scan_mid(const int* blocksum, int* blockoff, int NB, int* rowptr, int N, int E) {
  __shared__ int lds[1024];
  int tid = threadIdx.x;
  int v = (tid < NB) ? blocksum[tid] : 0;
  lds[tid] = v;
  __syncthreads();
  for (int off = 1; off < 1024; off <<= 1) {
    int t = (tid >= off) ? lds[tid - off] : 0;
    __syncthreads();
    lds[tid] += t;
    __syncthreads();
  }
  if (tid < NB) blockoff[tid] = lds[tid] - v;   // exclusive
  if (tid == 0) rowptr[N] = E;
}

__global__ void k_scan_out(const double* dpk, const int* blockoff, int* rowptr, int* cursor, int N) {
  __shared__ int lds[256];
  int tid = threadIdx.x, idx = blockIdx.x * 256 + tid;
  int v = (idx < N) ? (int)(dpk[idx] * (1.0 / CNTSC)) : 0;
  lds[tid] = v;
  __syncthreads();
  for (int off = 1; off < 256; off <<= 1) {
    int t = (tid >= off) ? lds[tid - off] : 0;
    __syncthreads();
    lds[tid] += t;
    __syncthreads();
  }
  if (idx < N) {
    int o = blockoff[blockIdx.x] + lds[tid] - v;
    rowptr[idx] = o;
    cursor[idx] = o;
  }
}

// CSR fill: erecA[p]={norm, dx, dy, dz} (d = pos_i - pos_j), erecI[p]=row
__global__ void k_fill(const int* eidx, const int* flag, const float* attr, const double* dpk,
                       const float* pos, int* cursor, float4* erecA, int* erecI, int E) {
  int e = blockIdx.x * 256 + threadIdx.x;
  if (e >= E) return;
  int is64 = *flag;
  int r  = load_idx(eidx, is64, e);
  int cl = load_idx(eidx, is64, (long long)E + e);
  double pr = dpk[r], pc = dpk[cl];
  double crd = (double)(int)(pr * (1.0 / CNTSC));
  double ccd = (double)(int)(pc * (1.0 / CNTSC));
  float dr = (float)(pr - crd * CNTSC);
  float dc = (float)(pc - ccd * CNTSC);
  float disr = (dr > 0.f) ? rsqrtf(dr) : 0.f;
  float disc = (dc > 0.f) ? rsqrtf(dc) : 0.f;
  float nrm = disr * disc * attr[e];
  float dx = pos[cl * 3 + 0] - pos[r * 3 + 0];
  float dy = pos[cl * 3 + 1] - pos[r * 3 + 1];
  float dz = pos[cl * 3 + 2] - pos[r * 3 + 2];
  int p = atomicAdd(&cursor[cl], 1);
  erecA[p] = make_float4(nrm, dx, dy, dz);
  erecI[p] = r;
}

// ---- MFMA node GEMM (v7) ----
// Block: 512 thr (8 waves), 32 nodes. A-rows (128): [0..31]=scalar, [32+32d..]=v_d.
// A staged in LDS as split-bf16 (hi|lo), XOR-swizzled 16B chunks. B (Wtg) loaded
// per-wave from global into frags. Wave wv owns cols [32wv..32wv+32) of both the
// Gs (rows 0..31) and Gv (rows 32..127) GEMMs. Split product: hi*hi+lo*hi+hi*lo.
// Epilogue: 4 row-group passes via the same 32KB LDS, packing uint4 records.
__global__ __launch_bounds__(512, 4) void k_gemm_rec(
    const float* __restrict__ scalar, const float* __restrict__ vector,
    const u16* __restrict__ Wtg,
    uint4* __restrict__ rec_i4, uint4* __restrict__ rec_j4, int N) {
  __shared__ u32 smem[8192];          // 32 KB: A-tile, then reused as epilogue stage
  u16*   Ax = (u16*)smem;
  float* Ep = (float*)smem;
  int tid = threadIdx.x, lane = tid & 63, wv = tid >> 6;
  int nb = blockIdx.x * 32;

  // ---- stage A: thread t: row = t>>2, 16 k's; convert fp32 -> bf16 hi/lo ----
  {
    int srow = tid >> 2, skq = tid & 3;
    const float* sp;
    int snode;
    if (srow < 32) { snode = nb + srow; sp = scalar + (size_t)snode * 64 + skq * 16; }
    else {
      int d = (srow - 32) >> 5, nl2 = (srow - 32) & 31;
      snode = nb + nl2;
      sp = vector + (size_t)snode * 192 + d * 64 + skq * 16;
    }
    bool valid = snode < N;
    u16 hi[16], lo[16];
    #pragma unroll
    for (int q = 0; q < 4; ++q) {
      float4 v = valid ? *(const float4*)(sp + 4 * q) : make_float4(0.f, 0.f, 0.f, 0.f);
      float xs[4] = {v.x, v.y, v.z, v.w};
      #pragma unroll
      for (int j = 0; j < 4; ++j) {
        u16 h = f2bf(xs[j]);
        hi[4 * q + j] = h;
        lo[4 * q + j] = f2bf(xs[j] - bf2f(h));
      }
    }
    int rs = srow & 7;
    #pragma unroll
    for (int c = 0; c < 2; ++c) {
      int lc = 2 * skq + c;
      uint4 wh, wl;
      wh.x = (u32)hi[8*c+0] | ((u32)hi[8*c+1] << 16);
      wh.y = (u32)hi[8*c+2] | ((u32)hi[8*c+3] << 16);
      wh.z = (u32)hi[8*c+4] | ((u32)hi[8*c+5] << 16);
      wh.w = (u32)hi[8*c+6] | ((u32)hi[8*c+7] << 16);
      wl.x = (u32)lo[8*c+0] | ((u32)lo[8*c+1] << 16);
      wl.y = (u32)lo[8*c+2] | ((u32)lo[8*c+3] << 16);
      wl.z = (u32)lo[8*c+4] | ((u32)lo[8*c+5] << 16);
      wl.w = (u32)lo[8*c+6] | ((u32)lo[8*c+7] << 16);
      *(uint4*)(Ax + srow * 128 + (lc ^ rs) * 8)        = wh;
      *(uint4*)(Ax + srow * 128 + ((8 + lc) ^ rs) * 8)  = wl;
    }
  }
  __syncthreads();

  // ---- MFMA main loop ----
  int c0 = wv * 32;
  int bl = lane & 15, bh = lane >> 4;
  f32x4 acc[8][2];
  #pragma unroll
  for (int mt = 0; mt < 8; ++mt)
    #pragma unroll
    for (int nt = 0; nt < 2; ++nt)
      acc[mt][nt] = (f32x4){0.f, 0.f, 0.f, 0.f};

  #pragma unroll
  for (int kh = 0; kh < 2; ++kh) {
    int k0 = kh * 32;
    bf16x8 Bh[2][2], Bl[2][2];
    #pragma unroll
    for (int rg = 0; rg < 2; ++rg)
      #pragma unroll
      for (int nt = 0; nt < 2; ++nt) {
        size_t rr = (size_t)(rg * 256 + c0 + nt * 16 + bl) * 128 + k0 + bh * 8;
        Bh[rg][nt] = *(const bf16x8*)(Wtg + rr);
        Bl[rg][nt] = *(const bf16x8*)(Wtg + rr + 64);
      }
    #pragma unroll
    for (int mt = 0; mt < 8; ++mt) {
      int row = mt * 16 + bl;
      int ch = (k0 >> 3) + bh, rs = row & 7;
      bf16x8 Ah = *(const bf16x8*)(Ax + row * 128 + (ch ^ rs) * 8);
      bf16x8 Al = *(const bf16x8*)(Ax + row * 128 + ((8 + ch) ^ rs) * 8);
      int rg = (mt < 2) ? 0 : 1;
      #pragma unroll
      for (int nt = 0; nt < 2; ++nt) {
        f32x4 a = acc[mt][nt];
        a = __builtin_amdgcn_mfma_f32_16x16x32_bf16(Ah, Bh[rg][nt], a, 0, 0, 0);
        a = __builtin_amdgcn_mfma_f32_16x16x32_bf16(Al, Bh[rg][nt], a, 0, 0, 0);
        a = __builtin_amdgcn_mfma_f32_16x16x32_bf16(Ah, Bl[rg][nt], a, 0, 0, 0);
        acc[mt][nt] = a;
      }
    }
  }

  // ---- epilogue: 4 passes (Gs, v0, v1, v2) through 32KB stage, pack uint4 ----
  int ech = tid & 63, eng = tid >> 6;
  uint4 oi[4], oj[4];
  #pragma unroll
  for (int pg = 0; pg < 4; ++pg) {
    __syncthreads();
    #pragma unroll
    for (int mm = 0; mm < 2; ++mm) {
      int mt = 2 * pg + mm;
      #pragma unroll
      for (int nt = 0; nt < 2; ++nt)
        #pragma unroll
        for (int r = 0; r < 4; ++r) {
          int rl = mm * 16 + bh * 4 + r;
          Ep[rl * 256 + c0 + nt * 16 + bl] = acc[mt][nt][r];
        }
    }
    __syncthreads();
    #pragma unroll
    for (int q = 0; q < 4; ++q) {
      int nl2 = eng + 8 * q;
      float vi0 = Ep[nl2 * 256 + ech];
      float vi1 = Ep[nl2 * 256 + 64 + ech];
      float vj0 = Ep[nl2 * 256 + 128 + ech];
      float vj1 = Ep[nl2 * 256 + 192 + ech];
      if (pg == 0) {
        oi[q].x = pk(vi0, vi1);                  oj[q].x = pk(vj0, vj1);
      } else if (pg == 1) {
        oi[q].y = (u32)f2bf(vi0);                oj[q].y = (u32)f2bf(vj0);
        oi[q].z = (u32)f2bf(vi1) << 16;          oj[q].z = (u32)f2bf(vj1) << 16;
      } else if (pg == 2) {
        oi[q].y |= (u32)f2bf(vi0) << 16;         oj[q].y |= (u32)f2bf(vj0) << 16;
        oi[q].w = (u32)f2bf(vi1);                oj[q].w = (u32)f2bf(vj1);
      } else {
        oi[q].z |= (u32)f2bf(vi0);               oj[q].z |= (u32)f2bf(vj0);
        oi[q].w |= (u32)f2bf(vi1) << 16;         oj[q].w |= (u32)f2bf(vj1) << 16;
      }
    }
  }
  #pragma unroll
  for (int q = 0; q < 4; ++q) {
    int node = nb + eng + 8 * q;
    if (node < N) {
      rec_i4[(size_t)node * 64 + ech] = oi[q];
      rec_j4[(size_t)node * 64 + ech] = oj[q];
    }
  }
}

// Fused hot kernel: one wave per node, 4-edge unrolled loop with 4-deep prefetch
// (rec_j gathers are HBM-latency bound), in-wave epilogue matvecs.
__global__ __launch_bounds__(512) void k_edges(
    const u16* __restrict__ rec_i, const u16* __restrict__ rec_j,
    const float4* __restrict__ erecA, const int* __restrict__ erecI,
    const int* __restrict__ rowptr,
    const float* __restrict__ scalar, const float* __restrict__ vector,
    const float* __restrict__ bss, const float* __restrict__ bvs,
    const float* __restrict__ bsv, const float* __restrict__ bsl,
    const u32* __restrict__ Wsl2g, const u32* __restrict__ Wpkg,
    const float* __restrict__ bcg,
    float* __restrict__ out_s, float* __restrict__ out_v, int N) {
  __shared__ u32 sWsl[4096];        // 16 KB
  __shared__ u32 sWv[2048];         // 8 KB  (Wvl_right only)
  __shared__ float sStage[8 * 128]; // 4 KB, wave-private epilogue stage
  int tid = threadIdx.x, lane = tid & 63, wv = tid >> 6;
  for (int o = tid; o < 4096; o += 512) sWsl[o] = Wsl2g[o];
  for (int o = tid; o < 2048; o += 512) sWv[o] = Wpkg[o];
  __syncthreads();   // the only block barrier

  int node = __builtin_amdgcn_readfirstlane((int)(blockIdx.x * 8) + wv);
  if (node >= N) node = N - 1;

  uint4 riv = *(const uint4*)(rec_i + ((size_t)node << 9) + lane * 8);
  float aiB  = lo16(riv.x) + bss[lane];
  float KciB = TWOL2E * (hi16(riv.x) + bsv[lane]);
  float Bvs  = bvs[lane];
  float bib0 = lo16(riv.y) + Bvs;
  float bib1 = hi16(riv.y) + Bvs;
  float bib2 = lo16(riv.z) + Bvs;
  float Pi0  = hi16(riv.z), Pi1 = lo16(riv.w), Pi2 = hi16(riv.w);
  float bsl_c = bsl[lane], bc_c = bcg[lane];

  float us = 0, uv = 0, t0 = 0, t1 = 0, t2 = 0, g0 = 0, g1 = 0, g2 = 0, wa = 0;
  int rp = rowptr[node], re = rowptr[node + 1];
  u32 lane16 = (u32)lane << 4;
  const char* rjb = (const char*)rec_j;

  // erecI has 64 zeroed ints of slack past E -> prefetch reads always valid
  u32 i0 = (u32)erecI[rp],     i1 = (u32)erecI[rp + 1];
  u32 i2 = (u32)erecI[rp + 2], i3 = (u32)erecI[rp + 3];
  uint4 pr0 = *(const uint4*)(rjb + ((i0 << 10) + lane16));
  uint4 pr1 = *(const uint4*)(rjb + ((i1 << 10) + lane16));
  uint4 pr2 = *(const uint4*)(rjb + ((i2 << 10) + lane16));
  uint4 pr3 = *(const uint4*)(rjb + ((i3 << 10) + lane16));
  int p = rp;
  #define EDGE_MATH(CUR, EV)                                                  \
    {                                                                         \
      float nrm = EV.x, dx = EV.y, dy = EV.z, dz = EV.w;                      \
      float aj  = lo16(CUR.x), cj  = hi16(CUR.x);                             \
      float bj0 = lo16(CUR.y), bj1 = hi16(CUR.y), bj2 = lo16(CUR.z);          \
      float rj0 = hi16(CUR.z), rj1 = lo16(CUR.w), rj2 = hi16(CUR.w);          \
      float xs  = aiB + aj;                                                   \
      float s2s = xs * frcp(1.f + exp2f(xs * NL2E));                          \
      float yv  = (bib0 + bj0) * dx;                                          \
      yv = fmaf(bib1 + bj1, dy, yv);                                          \
      yv = fmaf(bib2 + bj2, dz, yv);                                          \
      float v2s = yv * frcp(1.f + exp2f(yv * NL2E));                          \
      float qh  = fmaf(TWOL2E, cj, KciB);                                     \
      float th0 = fmaf(-2.f, frcp(1.f + exp2f(qh * dx)), 1.f);                \
      float th1 = fmaf(-2.f, frcp(1.f + exp2f(qh * dy)), 1.f);                \
      float th2 = fmaf(-2.f, frcp(1.f + exp2f(qh * dz)), 1.f);                \
      us = fmaf(nrm, s2s, us); uv = fmaf(nrm, v2s, uv);                       \
      t0 = fmaf(nrm, th0, t0); t1 = fmaf(nrm, th1, t1); t2 = fmaf(nrm, th2, t2);\
      g0 = fmaf(nrm, rj0, g0); g1 = fmaf(nrm, rj1, g1); g2 = fmaf(nrm, rj2, g2);\
      wa += nrm;                                                              \
    }
  for (; p + 3 < re; p += 4) {
    uint4 c0 = pr0, c1 = pr1, c2 = pr2, c3 = pr3;
    u32 n0 = (u32)erecI[p + 4], n1 = (u32)erecI[p + 5];
    u32 n2 = (u32)erecI[p + 6], n3 = (u32)erecI[p + 7];
    pr0 = *(const uint4*)(rjb + ((n0 << 10) + lane16));
    pr1 = *(const uint4*)(rjb + ((n1 << 10) + lane16));
    pr2 = *(const uint4*)(rjb + ((n2 << 10) + lane16));
    pr3 = *(const uint4*)(rjb + ((n3 << 10) + lane16));
    float4 e0 = erecA[p],     e1 = erecA[p + 1];
    float4 e2 = erecA[p + 2], e3 = erecA[p + 3];
    EDGE_MATH(c0, e0)
    EDGE_MATH(c1, e1)
    EDGE_MATH(c2, e2)
    EDGE_MATH(c3, e3)
  }
  if (p < re)     { float4 e = erecA[p];     EDGE_MATH(pr0, e) }
  if (p + 1 < re) { float4 e = erecA[p + 1]; EDGE_MATH(pr1, e) }
  if (p + 2 < re) { float4 e = erecA[p + 2]; EDGE_MATH(pr2, e) }
  #undef EDGE_MATH

  // ---- epilogue: scalar head (wave-local, no block barrier) ----
  float* mys = &sStage[wv * 128];
  mys[lane] = us; mys[64 + lane] = uv;
  __threadfence_block();
  float acc = wa * bsl_c;
  #pragma unroll
  for (int g = 0; g < 32; ++g) {
    float4 u = *(const float4*)&mys[4 * g];
    uint2 w = *(const uint2*)&sWsl[(g * 64 + lane) * 2];
    acc = fmaf(u.x, lo16(w.x), acc);
    acc = fmaf(u.y, hi16(w.x), acc);
    acc = fmaf(u.z, lo16(w.y), acc);
    acc = fmaf(u.w, hi16(w.y), acc);
  }
  size_t so = ((size_t)node << 6) + lane;
  out_s[so] = acc * frcp(1.f + exp2f(acc * NL2E)) + scalar[so];

  // ---- epilogue: vector head (t-part matvec only; x,y parts precomputed) ----
  float gg[3] = {g0, g1, g2}, tt[3] = {t0, t1, t2}, Pi[3] = {Pi0, Pi1, Pi2};
  #pragma unroll
  for (int d = 0; d < 3; ++d) {
    size_t vo = (((size_t)node * 3 + d) << 6) + lane;
    float vid = vector[vo];
    __threadfence_block();
    mys[lane] = tt[d];
    __threadfence_block();
    float a2 = fmaf(wa, bc_c + Pi[d], gg[d]);
    #pragma unroll
    for (int g = 0; g < 16; ++g) {
      float4 tu = *(const float4*)&mys[4 * g];
      uint2 w = *(const uint2*)&sWv[(g * 64 + lane) * 2];
      a2 = fmaf(tu.x, lo16(w.x), a2); a2 = fmaf(tu.y, hi16(w.x), a2);
      a2 = fmaf(tu.z, lo16(w.y), a2); a2 = fmaf(tu.w, hi16(w.y), a2);
    }
    float th = fmaf(-2.f, frcp(1.f + exp2f(TWOL2E * a2)), 1.f);
    out_v[vo] = th + vid;
  }
}

extern "C" void kernel_launch(void* const* d_in, const int* in_sizes, int n_in,
                              void* d_out, int out_size, void* d_ws, size_t ws_size,
                              hipStream_t stream) {
  const float* scalar   = (const float*)d_in[0];
  const float* vector   = (const float*)d_in[1];
  const float* position = (const float*)d_in[2];
  const int*   eidx     = (const int*)d_in[3];
  const float* attr     = (const float*)d_in[4];
  const float* Wss = (const float*)d_in[5];
  const float* bss = (const float*)d_in[6];
  const float* Wvs = (const float*)d_in[7];
  const float* bvs = (const float*)d_in[8];
  const float* Wsl = (const float*)d_in[9];
  const float* bsl = (const float*)d_in[10];
  const float* Wsv = (const float*)d_in[11];
  const float* bsv = (const float*)d_in[12];
  const float* Wvv = (const float*)d_in[13];
  const float* bvv = (const float*)d_in[14];
  const float* Wvl = (const float*)d_in[15];
  const float* bvl = (const float*)d_in[16];

  int N = in_sizes[0] / 64;
  int E = in_sizes[4];
  int NB = (N + 255) / 256;   // scan blocks (must be <= 1024)

  char* wsb = (char*)d_ws;
  size_t off = 0;
  auto alloc = [&](size_t bytes) -> char* {
    char* p = wsb + off;
    off += (bytes + 255) & ~(size_t)255;
    return p;
  };
  double* dpk    = (double*)alloc((size_t)N * 8);
  int*    rowptr = (int*)alloc((size_t)(N + 1) * 4);
  int*    cursor = (int*)alloc((size_t)N * 4);
  int*    blocksum = (int*)alloc((size_t)NB * 4);
  int*    blockoff = (int*)alloc((size_t)NB * 4);
  float4* erecA  = (float4*)alloc((size_t)E * 16);
  int*    erecI  = (int*)alloc((size_t)(E + 64) * 4);   // +slack for prefetch reads
  u16*    rec_i  = (u16*)alloc((size_t)N * 512 * 2);
  u16*    rec_j  = (u16*)alloc((size_t)N * 512 * 2);
  u16*    Wtg    = (u16*)alloc(512 * 128 * 2);          // 128 KB split-bf16 W^T
  u32*    Wsl2   = (u32*)alloc(4096 * 4);
  u32*    Wpk    = (u32*)alloc(2048 * 4);
  float*  WcTmp  = (float*)alloc(64 * 128 * 4);
  float*  bc     = (float*)alloc(64 * 4);
  int*    flag   = (int*)alloc(4);
  (void)ws_size; (void)n_in; (void)out_size;

  // zero dpk and the erecI prefetch slack
  hipMemsetAsync(dpk, 0, (size_t)((char*)rowptr - (char*)dpk), stream);
  hipMemsetAsync(erecI + E, 0, 64 * 4, stream);

  k_prep1<<<34, 256, 0, stream>>>(Wvl, Wvv, bvv, bvl, eidx, E, flag, WcTmp, bc);
  k_prep2<<<11, 256, 0, stream>>>(Wss, Wsv, Wvs, Wsl, Wvl, WcTmp, Wsl2, Wpk, Wtg);
  k_deg<<<(E + 255) / 256, 256, 0, stream>>>(eidx, flag, attr, dpk, E);
  k_scan_red<<<NB, 256, 0, stream>>>(dpk, blocksum, N);
  k_scan_mid<<<1, 1024, 0, stream>>>(blocksum, blockoff, NB, rowptr, N, E);
  k_scan_out<<<NB, 256, 0, stream>>>(dpk, blockoff, rowptr, cursor, N);
  k_fill<<<(E + 255) / 256, 256, 0, stream>>>(eidx, flag, attr, dpk, position, cursor, erecA, erecI, E);
  k_gemm_rec<<<(N + 31) / 32, 512, 0, stream>>>(scalar, vector, Wtg,
                                                (uint4*)rec_i, (uint4*)rec_j, N);
  k_edges<<<(N + 7) / 8, 512, 0, stream>>>(rec_i, rec_j, erecA, erecI, rowptr,
                                           scalar, vector, bss, bvs, bsv, bsl,
                                           Wsl2, Wpk, bc,
                                           (float*)d_out, (float*)d_out + (size_t)N * 64, N);
}

// Round 8
// 439.957 us; speedup vs baseline: 1.3967x; 1.0280x over previous
//
#include <hip/hip_runtime.h>
#include <cstdint>
#include <cstddef>

typedef unsigned int   u32;
typedef unsigned short u16;
typedef __attribute__((ext_vector_type(8))) short bf16x8;
typedef __attribute__((ext_vector_type(4))) float f32x4;

__device__ __forceinline__ float bf2f(u32 bits16) { return __uint_as_float(bits16 << 16); }
__device__ __forceinline__ u16 f2bf(float f) {
  u32 u = __float_as_uint(f);
  u = u + 0x7FFFu + ((u >> 16) & 1u);   // round-to-nearest-even
  return (u16)(u >> 16);
}
__device__ __forceinline__ u32 pk(float a, float b) {
  return (u32)f2bf(a) | ((u32)f2bf(b) << 16);
}
__device__ __forceinline__ float lo16(u32 w) { return bf2f(w & 0xFFFFu); }
__device__ __forceinline__ float hi16(u32 w) { return bf2f(w >> 16); }
__device__ __forceinline__ float frcp(float x) { return __builtin_amdgcn_rcpf(x); }

#define NL2E   (-1.4426950408889634f)
#define TWOL2E (2.8853900817779268f)
#define CNTSC  1073741824.0            // 2^30: cnt encoded above deg in one double

__device__ __forceinline__ int load_idx(const int* eidx, int is64, long long pos) {
  if (is64) return (int)(((const long long*)eidx)[pos]);
  return eidx[pos];
}

// ---- prep stage 1 (grid 34): WcTmp = Wvl_left @ Wvv, edge-width detect, bc ----
__global__ void k_prep1(const float* Wvl, const float* Wvv,
                        const float* bvv, const float* bvl,
                        const int* eidx, int E, int* flag,
                        float* WcTmp, float* bc) {
  int b = blockIdx.x, tid = threadIdx.x;
  if (b < 32) {
    int c = 2 * b + (tid >> 7), kk = tid & 127;
    float s = 0.f;
    for (int m = 0; m < 64; ++m) s += Wvl[c * 128 + m] * Wvv[m * 128 + kk];
    WcTmp[c * 128 + kk] = s;
  } else if (b == 32) {
    __shared__ int zc;
    if (tid == 0) zc = 0;
    __syncthreads();
    int n = (E < 1024) ? E : 1024;
    int local = 0;
    for (int i = tid; i < n; i += 256) {
      if (eidx[2 * i + 1] == 0) local++;   // high words if int64 (all 0)
    }
    atomicAdd(&zc, local);
    __syncthreads();
    if (tid == 0) *flag = (zc >= (n >> 1)) ? 1 : 0;
  } else if (b == 33) {
    if (tid < 64) {
      float s = 0.f;
      for (int m = 0; m < 64; ++m) s += Wvl[tid * 128 + m] * bvv[m];
      bc[tid] = s + bvl[tid];
    }
  }
}

// ---- prep stage 2 (grid 11) ----
// b0..1: Wsl2 bf16 table; b2: Wpk; b3..10: Wtg split-bf16 W^T for the MFMA GEMM.
// Wtg rows r (u16[512][128], hi at k, lo at 64+k):
//   r<256 (Gs cols): g=r>>6: 0 A_i=Wss_L, 1 C_i=Wsv_L, 2 A_j=Wss_R, 3 C_j=Wsv_R
//   r>=256 (Gv cols): g: 0 B_i=Wvs_L, 1 P_i=Wc_L, 2 B_j=Wvs_R, 3 P_j=Wc_R
__global__ void k_prep2(const float* Wss, const float* Wsv, const float* Wvs,
                        const float* Wsl, const float* Wvl, const float* WcTmp,
                        u32* Wsl2, u32* Wpk, u16* Wtg) {
  int b = blockIdx.x, tid = threadIdx.x;
  if (b < 2) {
    for (int i = 0; i < 8; ++i) {
      int o = b * 2048 + i * 256 + tid;
      int h = o & 1, c = (o >> 1) & 63, g = o >> 7;
      int k = 4 * g + 2 * h;
      Wsl2[o] = pk(Wsl[c * 128 + k], Wsl[c * 128 + k + 1]);
    }
  } else if (b == 2) {
    for (int i = 0; i < 8; ++i) {
      int o = i * 256 + tid;
      int h = o & 1, c = (o >> 1) & 63, g = o >> 7;
      int k = 4 * g + 2 * h;
      Wpk[o] = pk(Wvl[c * 128 + 64 + k], Wvl[c * 128 + 64 + k + 1]);
    }
  } else {
    for (int i = 0; i < 16; ++i) {
      int p = (b - 3) * 4096 + i * 256 + tid;   // 0..32767
      int r = p >> 6, k = p & 63;
      int g = (r >> 6) & 3, ch = r & 63;
      int src = ch * 128 + ((g & 2) ? 64 : 0) + k;
      float w;
      if (r < 256) w = (g & 1) ? Wsv[src] : Wss[src];
      else         w = (g & 1) ? WcTmp[src] : Wvs[src];
      u16 h = f2bf(w);
      Wtg[r * 128 + k] = h;
      Wtg[r * 128 + 64 + k] = f2bf(w - bf2f(h));
    }
  }
}

// one fp64 atomic per edge: dpk[col] += attr + 2^30  (cnt in high part, deg in low)
__global__ void k_deg(const int* eidx, const int* flag, const float* attr,
                      double* dpk, int E) {
  int e = blockIdx.x * 256 + threadIdx.x;
  if (e >= E) return;
  int is64 = *flag;
  int col = load_idx(eidx, is64, (long long)E + e);
  atomicAdd(&dpk[col], (double)attr[e] + CNTSC);
}

// ---- multi-block exclusive scan of cnt -> rowptr, cursor; also emits dis[n] ----
__global__ void k_scan_red(const double* dpk, int* blocksum, float* dis, int N) {
  __shared__ int lds[256];
  int tid = threadIdx.x, idx = blockIdx.x * 256 + tid;
  int c = 0;
  if (idx < N) {
    double p = dpk[idx];
    c = (int)(p * (1.0 / CNTSC));
    float dg = (float)(p - (double)c * CNTSC);
    dis[idx] = (dg > 0.f) ? rsqrtf(dg) : 0.f;
  }
  lds[tid] = c;
  __syncthreads();
  for (int off = 128; off > 0; off >>= 1) {
    if (tid < off) lds[tid] += lds[tid + off];
    __syncthreads();
  }
  if (tid == 0) blocksum[blockIdx.x] = lds[0];
}

__global__ void k_scan_mid(const int* blocksum, int* blockoff, int NB, int* rowptr, int N, int E) {
  __shared__ int lds[1024];
  int tid = threadIdx.x;
  int v = (tid < NB) ? blocksum[tid] : 0;
  lds[tid] = v;
  __syncthreads();
  for (int off = 1; off < 1024; off <<= 1) {
    int t = (tid >= off) ? lds[tid - off] : 0;
    __syncthreads();
    lds[tid] += t;
    __syncthreads();
  }
  if (tid < NB) blockoff[tid] = lds[tid] - v;   // exclusive
  if (tid == 0) rowptr[N] = E;
}

__global__ void k_scan_out(const double* dpk, const int* blockoff, int* rowptr, int* cursor, int N) {
  __shared__ int lds[256];
  int tid = threadIdx.x, idx = blockIdx.x * 256 + tid;
  int v = (idx < N) ? (int)(dpk[idx] * (1.0 / CNTSC)) : 0;
  lds[tid] = v;
  __syncthreads();
  for (int off = 1; off < 256; off <<= 1) {
    int t = (tid >= off) ? lds[tid - off] : 0;
    __syncthreads();
    lds[tid] += t;
    __syncthreads();
  }
  if (idx < N) {
    int o = blockoff[blockIdx.x] + lds[tid] - v;
    rowptr[idx] = o;
    cursor[idx] = o;
  }
}

// CSR fill: erecA[p]={norm, dx, dy, dz} (d = pos_i - pos_j), erecI[p]=row
__global__ void k_fill(const int* eidx, const int* flag, const float* attr, const float* dis,
                       const float* pos, int* cursor, float4* erecA, int* erecI, int E) {
  int e = blockIdx.x * 256 + threadIdx.x;
  if (e >= E) return;
  int is64 = *flag;
  int r  = load_idx(eidx, is64, e);
  int cl = load_idx(eidx, is64, (long long)E + e);
  float nrm = dis[r] * dis[cl] * attr[e];
  float dx = pos[cl * 3 + 0] - pos[r * 3 + 0];
  float dy = pos[cl * 3 + 1] - pos[r * 3 + 1];
  float dz = pos[cl * 3 + 2] - pos[r * 3 + 2];
  int p = atomicAdd(&cursor[cl], 1);
  erecA[p] = make_float4(nrm, dx, dy, dz);
  erecI[p] = r;
}

// ---- MFMA node GEMM (v7) ----
// Block: 512 thr (8 waves), 32 nodes. A-rows (128): [0..31]=scalar, [32+32d..]=v_d.
// A staged in LDS as split-bf16 (hi|lo), XOR-swizzled 16B chunks. B (Wtg) loaded
// per-wave from global into frags. Wave wv owns cols [32wv..32wv+32) of both the
// Gs (rows 0..31) and Gv (rows 32..127) GEMMs. Split product: hi*hi+lo*hi+hi*lo.
// Epilogue: 4 row-group passes via the same 32KB LDS, packing uint4 records.
__global__ __launch_bounds__(512, 4) void k_gemm_rec(
    const float* __restrict__ scalar, const float* __restrict__ vector,
    const u16* __restrict__ Wtg,
    uint4* __restrict__ rec_i4, uint4* __restrict__ rec_j4, int N) {
  __shared__ u32 smem[8192];          // 32 KB: A-tile, then reused as epilogue stage
  u16*   Ax = (u16*)smem;
  float* Ep = (float*)smem;
  int tid = threadIdx.x, lane = tid & 63, wv = tid >> 6;
  int nb = blockIdx.x * 32;

  // ---- stage A: thread t: row = t>>2, 16 k's; convert fp32 -> bf16 hi/lo ----
  {
    int srow = tid >> 2, skq = tid & 3;
    const float* sp;
    int snode;
    if (srow < 32) { snode = nb + srow; sp = scalar + (size_t)snode * 64 + skq * 16; }
    else {
      int d = (srow - 32) >> 5, nl2 = (srow - 32) & 31;
      snode = nb + nl2;
      sp = vector + (size_t)snode * 192 + d * 64 + skq * 16;
    }
    bool valid = snode < N;
    u16 hi[16], lo[16];
    #pragma unroll
    for (int q = 0; q < 4; ++q) {
      float4 v = valid ? *(const float4*)(sp + 4 * q) : make_float4(0.f, 0.f, 0.f, 0.f);
      float xs[4] = {v.x, v.y, v.z, v.w};
      #pragma unroll
      for (int j = 0; j < 4; ++j) {
        u16 h = f2bf(xs[j]);
        hi[4 * q + j] = h;
        lo[4 * q + j] = f2bf(xs[j] - bf2f(h));
      }
    }
    int rs = srow & 7;
    #pragma unroll
    for (int c = 0; c < 2; ++c) {
      int lc = 2 * skq + c;
      uint4 wh, wl;
      wh.x = (u32)hi[8*c+0] | ((u32)hi[8*c+1] << 16);
      wh.y = (u32)hi[8*c+2] | ((u32)hi[8*c+3] << 16);
      wh.z = (u32)hi[8*c+4] | ((u32)hi[8*c+5] << 16);
      wh.w = (u32)hi[8*c+6] | ((u32)hi[8*c+7] << 16);
      wl.x = (u32)lo[8*c+0] | ((u32)lo[8*c+1] << 16);
      wl.y = (u32)lo[8*c+2] | ((u32)lo[8*c+3] << 16);
      wl.z = (u32)lo[8*c+4] | ((u32)lo[8*c+5] << 16);
      wl.w = (u32)lo[8*c+6] | ((u32)lo[8*c+7] << 16);
      *(uint4*)(Ax + srow * 128 + (lc ^ rs) * 8)        = wh;
      *(uint4*)(Ax + srow * 128 + ((8 + lc) ^ rs) * 8)  = wl;
    }
  }
  __syncthreads();

  // ---- MFMA main loop ----
  int c0 = wv * 32;
  int bl = lane & 15, bh = lane >> 4;
  f32x4 acc[8][2];
  #pragma unroll
  for (int mt = 0; mt < 8; ++mt)
    #pragma unroll
    for (int nt = 0; nt < 2; ++nt)
      acc[mt][nt] = (f32x4){0.f, 0.f, 0.f, 0.f};

  #pragma unroll
  for (int kh = 0; kh < 2; ++kh) {
    int k0 = kh * 32;
    bf16x8 Bh[2][2], Bl[2][2];
    #pragma unroll
    for (int rg = 0; rg < 2; ++rg)
      #pragma unroll
      for (int nt = 0; nt < 2; ++nt) {
        size_t rr = (size_t)(rg * 256 + c0 + nt * 16 + bl) * 128 + k0 + bh * 8;
        Bh[rg][nt] = *(const bf16x8*)(Wtg + rr);
        Bl[rg][nt] = *(const bf16x8*)(Wtg + rr + 64);
      }
    #pragma unroll
    for (int mt = 0; mt < 8; ++mt) {
      int row = mt * 16 + bl;
      int ch = (k0 >> 3) + bh, rs = row & 7;
      bf16x8 Ah = *(const bf16x8*)(Ax + row * 128 + (ch ^ rs) * 8);
      bf16x8 Al = *(const bf16x8*)(Ax + row * 128 + ((8 + ch) ^ rs) * 8);
      int rg = (mt < 2) ? 0 : 1;
      #pragma unroll
      for (int nt = 0; nt < 2; ++nt) {
        f32x4 a = acc[mt][nt];
        a = __builtin_amdgcn_mfma_f32_16x16x32_bf16(Ah, Bh[rg][nt], a, 0, 0, 0);
        a = __builtin_amdgcn_mfma_f32_16x16x32_bf16(Al, Bh[rg][nt], a, 0, 0, 0);
        a = __builtin_amdgcn_mfma_f32_16x16x32_bf16(Ah, Bl[rg][nt], a, 0, 0, 0);
        acc[mt][nt] = a;
      }
    }
  }

  // ---- epilogue: 4 passes (Gs, v0, v1, v2) through 32KB stage, pack uint4 ----
  int ech = tid & 63, eng = tid >> 6;
  uint4 oi[4], oj[4];
  #pragma unroll
  for (int pg = 0; pg < 4; ++pg) {
    __syncthreads();
    #pragma unroll
    for (int mm = 0; mm < 2; ++mm) {
      int mt = 2 * pg + mm;
      #pragma unroll
      for (int nt = 0; nt < 2; ++nt)
        #pragma unroll
        for (int r = 0; r < 4; ++r) {
          int rl = mm * 16 + bh * 4 + r;
          Ep[rl * 256 + c0 + nt * 16 + bl] = acc[mt][nt][r];
        }
    }
    __syncthreads();
    #pragma unroll
    for (int q = 0; q < 4; ++q) {
      int nl2 = eng + 8 * q;
      float vi0 = Ep[nl2 * 256 + ech];
      float vi1 = Ep[nl2 * 256 + 64 + ech];
      float vj0 = Ep[nl2 * 256 + 128 + ech];
      float vj1 = Ep[nl2 * 256 + 192 + ech];
      if (pg == 0) {
        oi[q].x = pk(vi0, vi1);                  oj[q].x = pk(vj0, vj1);
      } else if (pg == 1) {
        oi[q].y = (u32)f2bf(vi0);                oj[q].y = (u32)f2bf(vj0);
        oi[q].z = (u32)f2bf(vi1) << 16;          oj[q].z = (u32)f2bf(vj1) << 16;
      } else if (pg == 2) {
        oi[q].y |= (u32)f2bf(vi0) << 16;         oj[q].y |= (u32)f2bf(vj0) << 16;
        oi[q].w = (u32)f2bf(vi1);                oj[q].w = (u32)f2bf(vj1);
      } else {
        oi[q].z |= (u32)f2bf(vi0);               oj[q].z |= (u32)f2bf(vj0);
        oi[q].w |= (u32)f2bf(vi1) << 16;         oj[q].w |= (u32)f2bf(vj1) << 16;
      }
    }
  }
  #pragma unroll
  for (int q = 0; q < 4; ++q) {
    int node = nb + eng + 8 * q;
    if (node < N) {
      rec_i4[(size_t)node * 64 + ech] = oi[q];
      rec_j4[(size_t)node * 64 + ech] = oj[q];
    }
  }
}

// Fused hot kernel: one wave per node, wave-uniform scalar edge metadata,
// 2-edge unrolled loop with double prefetch, in-wave epilogue matvecs.
// (r3-proven loop structure; exp2f-hoisted tanh args; no clamps via zeroed slack.)
__global__ __launch_bounds__(512) void k_edges(
    const u16* __restrict__ rec_i, const u16* __restrict__ rec_j,
    const float4* __restrict__ erecA, const int* __restrict__ erecI,
    const int* __restrict__ rowptr,
    const float* __restrict__ scalar, const float* __restrict__ vector,
    const float* __restrict__ bss, const float* __restrict__ bvs,
    const float* __restrict__ bsv, const float* __restrict__ bsl,
    const u32* __restrict__ Wsl2g, const u32* __restrict__ Wpkg,
    const float* __restrict__ bcg,
    float* __restrict__ out_s, float* __restrict__ out_v, int N) {
  __shared__ u32 sWsl[4096];        // 16 KB
  __shared__ u32 sWv[2048];         // 8 KB  (Wvl_right only)
  __shared__ float sStage[8 * 128]; // 4 KB, wave-private epilogue stage
  int tid = threadIdx.x, lane = tid & 63, wv = tid >> 6;
  for (int o = tid; o < 4096; o += 512) sWsl[o] = Wsl2g[o];
  for (int o = tid; o < 2048; o += 512) sWv[o] = Wpkg[o];
  __syncthreads();   // the only block barrier

  int node = __builtin_amdgcn_readfirstlane((int)(blockIdx.x * 8) + wv);
  if (node >= N) node = N - 1;

  uint4 riv = *(const uint4*)(rec_i + ((size_t)node << 9) + lane * 8);
  float aiB  = lo16(riv.x) + bss[lane];
  float KciB = TWOL2E * (hi16(riv.x) + bsv[lane]);
  float Bvs  = bvs[lane];
  float bib0 = lo16(riv.y) + Bvs;
  float bib1 = hi16(riv.y) + Bvs;
  float bib2 = lo16(riv.z) + Bvs;
  float Pi0  = hi16(riv.z), Pi1 = lo16(riv.w), Pi2 = hi16(riv.w);
  float bsl_c = bsl[lane], bc_c = bcg[lane];

  float us = 0, uv = 0, t0 = 0, t1 = 0, t2 = 0, g0 = 0, g1 = 0, g2 = 0, wa = 0;
  int rp = rowptr[node], re = rowptr[node + 1];
  u32 lane16 = (u32)lane << 4;
  const char* rjb = (const char*)rec_j;

  // erecI has 64 zeroed ints of slack past E -> prefetch reads always valid
  u32 ra = (u32)erecI[rp];
  u32 rb = (u32)erecI[rp + 1];
  uint4 pre0 = *(const uint4*)(rjb + ((ra << 10) + lane16));
  uint4 pre1 = *(const uint4*)(rjb + ((rb << 10) + lane16));
  int p = rp;
  #define EDGE_MATH(CUR, EV)                                                  \
    {                                                                         \
      float nrm = EV.x, dx = EV.y, dy = EV.z, dz = EV.w;                      \
      float aj  = lo16(CUR.x), cj  = hi16(CUR.x);                             \
      float bj0 = lo16(CUR.y), bj1 = hi16(CUR.y), bj2 = lo16(CUR.z);          \
      float rj0 = hi16(CUR.z), rj1 = lo16(CUR.w), rj2 = hi16(CUR.w);          \
      float xs  = aiB + aj;                                                   \
      float s2s = xs * frcp(1.f + exp2f(xs * NL2E));                          \
      float yv  = (bib0 + bj0) * dx;                                          \
      yv = fmaf(bib1 + bj1, dy, yv);                                          \
      yv = fmaf(bib2 + bj2, dz, yv);                                          \
      float v2s = yv * frcp(1.f + exp2f(yv * NL2E));                          \
      float qh  = fmaf(TWOL2E, cj, KciB);                                     \
      float th0 = fmaf(-2.f, frcp(1.f + exp2f(qh * dx)), 1.f);                \
      float th1 = fmaf(-2.f, frcp(1.f + exp2f(qh * dy)), 1.f);                \
      float th2 = fmaf(-2.f, frcp(1.f + exp2f(qh * dz)), 1.f);                \
      us = fmaf(nrm, s2s, us); uv = fmaf(nrm, v2s, uv);                       \
      t0 = fmaf(nrm, th0, t0); t1 = fmaf(nrm, th1, t1); t2 = fmaf(nrm, th2, t2);\
      g0 = fmaf(nrm, rj0, g0); g1 = fmaf(nrm, rj1, g1); g2 = fmaf(nrm, rj2, g2);\
      wa += nrm;                                                              \
    }
  for (; p + 1 < re; p += 2) {
    uint4 cur0 = pre0, cur1 = pre1;
    u32 rn0 = (u32)erecI[p + 2];
    u32 rn1 = (u32)erecI[p + 3];
    pre0 = *(const uint4*)(rjb + ((rn0 << 10) + lane16));
    pre1 = *(const uint4*)(rjb + ((rn1 << 10) + lane16));
    float4 e0 = erecA[p];
    float4 e1 = erecA[p + 1];
    EDGE_MATH(cur0, e0)
    EDGE_MATH(cur1, e1)
  }
  if (p < re) {
    uint4 cur0 = pre0;
    float4 e0 = erecA[p];
    EDGE_MATH(cur0, e0)
  }
  #undef EDGE_MATH

  // ---- epilogue: scalar head (wave-local, no block barrier) ----
  float* mys = &sStage[wv * 128];
  mys[lane] = us; mys[64 + lane] = uv;
  __threadfence_block();
  float acc = wa * bsl_c;
  #pragma unroll
  for (int g = 0; g < 32; ++g) {
    float4 u = *(const float4*)&mys[4 * g];
    uint2 w = *(const uint2*)&sWsl[(g * 64 + lane) * 2];
    acc = fmaf(u.x, lo16(w.x), acc);
    acc = fmaf(u.y, hi16(w.x), acc);
    acc = fmaf(u.z, lo16(w.y), acc);
    acc = fmaf(u.w, hi16(w.y), acc);
  }
  size_t so = ((size_t)node << 6) + lane;
  out_s[so] = acc * frcp(1.f + exp2f(acc * NL2E)) + scalar[so];

  // ---- epilogue: vector head (t-part matvec only; x,y parts precomputed) ----
  float gg[3] = {g0, g1, g2}, tt[3] = {t0, t1, t2}, Pi[3] = {Pi0, Pi1, Pi2};
  #pragma unroll
  for (int d = 0; d < 3; ++d) {
    size_t vo = (((size_t)node * 3 + d) << 6) + lane;
    float vid = vector[vo];
    __threadfence_block();
    mys[lane] = tt[d];
    __threadfence_block();
    float a2 = fmaf(wa, bc_c + Pi[d], gg[d]);
    #pragma unroll
    for (int g = 0; g < 16; ++g) {
      float4 tu = *(const float4*)&mys[4 * g];
      uint2 w = *(const uint2*)&sWv[(g * 64 + lane) * 2];
      a2 = fmaf(tu.x, lo16(w.x), a2); a2 = fmaf(tu.y, hi16(w.x), a2);
      a2 = fmaf(tu.z, lo16(w.y), a2); a2 = fmaf(tu.w, hi16(w.y), a2);
    }
    float th = fmaf(-2.f, frcp(1.f + exp2f(TWOL2E * a2)), 1.f);
    out_v[vo] = th + vid;
  }
}

extern "C" void kernel_launch(void* const* d_in, const int* in_sizes, int n_in,
                              void* d_out, int out_size, void* d_ws, size_t ws_size,
                              hipStream_t stream) {
  const float* scalar   = (const float*)d_in[0];
  const float* vector   = (const float*)d_in[1];
  const float* position = (const float*)d_in[2];
  const int*   eidx     = (const int*)d_in[3];
  const float* attr     = (const float*)d_in[4];
  const float* Wss = (const float*)d_in[5];
  const float* bss = (const float*)d_in[6];
  const float* Wvs = (const float*)d_in[7];
  const float* bvs = (const float*)d_in[8];
  const float* Wsl = (const float*)d_in[9];
  const float* bsl = (const float*)d_in[10];
  const float* Wsv = (const float*)d_in[11];
  const float* bsv = (const float*)d_in[12];
  const float* Wvv = (const float*)d_in[13];
  const float* bvv = (const float*)d_in[14];
  const float* Wvl = (const float*)d_in[15];
  const float* bvl = (const float*)d_in[16];

  int N = in_sizes[0] / 64;
  int E = in_sizes[4];
  int NB = (N + 255) / 256;   // scan blocks (must be <= 1024)

  char* wsb = (char*)d_ws;
  size_t off = 0;
  auto alloc = [&](size_t bytes) -> char* {
    char* p = wsb + off;
    off += (bytes + 255) & ~(size_t)255;
    return p;
  };
  double* dpk    = (double*)alloc((size_t)N * 8);
  int*    rowptr = (int*)alloc((size_t)(N + 1) * 4);
  int*    cursor = (int*)alloc((size_t)N * 4);
  float*  dis    = (float*)alloc((size_t)N * 4);
  int*    blocksum = (int*)alloc((size_t)NB * 4);
  int*    blockoff = (int*)alloc((size_t)NB * 4);
  float4* erecA  = (float4*)alloc((size_t)E * 16);
  int*    erecI  = (int*)alloc((size_t)(E + 64) * 4);   // +slack for prefetch reads
  u16*    rec_i  = (u16*)alloc((size_t)N * 512 * 2);
  u16*    rec_j  = (u16*)alloc((size_t)N * 512 * 2);
  u16*    Wtg    = (u16*)alloc(512 * 128 * 2);          // 128 KB split-bf16 W^T
  u32*    Wsl2   = (u32*)alloc(4096 * 4);
  u32*    Wpk    = (u32*)alloc(2048 * 4);
  float*  WcTmp  = (float*)alloc(64 * 128 * 4);
  float*  bc     = (float*)alloc(64 * 4);
  int*    flag   = (int*)alloc(4);
  (void)ws_size; (void)n_in; (void)out_size;

  // zero dpk and the erecI prefetch slack
  hipMemsetAsync(dpk, 0, (size_t)((char*)rowptr - (char*)dpk), stream);
  hipMemsetAsync(erecI + E, 0, 64 * 4, stream);

  k_prep1<<<34, 256, 0, stream>>>(Wvl, Wvv, bvv, bvl, eidx, E, flag, WcTmp, bc);
  k_prep2<<<11, 256, 0, stream>>>(Wss, Wsv, Wvs, Wsl, Wvl, WcTmp, Wsl2, Wpk, Wtg);
  k_deg<<<(E + 255) / 256, 256, 0, stream>>>(eidx, flag, attr, dpk, E);
  k_scan_red<<<NB, 256, 0, stream>>>(dpk, blocksum, dis, N);
  k_scan_mid<<<1, 1024, 0, stream>>>(blocksum, blockoff, NB, rowptr, N, E);
  k_scan_out<<<NB, 256, 0, stream>>>(dpk, blockoff, rowptr, cursor, N);
  k_fill<<<(E + 255) / 256, 256, 0, stream>>>(eidx, flag, attr, dis, position, cursor, erecA, erecI, E);
  k_gemm_rec<<<(N + 31) / 32, 512, 0, stream>>>(scalar, vector, Wtg,
                                                (uint4*)rec_i, (uint4*)rec_j, N);
  k_edges<<<(N + 7) / 8, 512, 0, stream>>>(rec_i, rec_j, erecA, erecI, rowptr,
                                           scalar, vector, bss, bvs, bsv, bsl,
                                           Wsl2, Wpk, bc,
                                           (float*)d_out, (float*)d_out + (size_t)N * 64, N);
}

// Round 9
// 431.396 us; speedup vs baseline: 1.4244x; 1.0198x over previous
//
#include <hip/hip_runtime.h>
#include <cstdint>
#include <cstddef>

typedef unsigned int   u32;
typedef unsigned short u16;
typedef __attribute__((ext_vector_type(8))) short bf16x8;
typedef __attribute__((ext_vector_type(4))) float f32x4;

__device__ __forceinline__ float bf2f(u32 bits16) { return __uint_as_float(bits16 << 16); }
__device__ __forceinline__ u16 f2bf(float f) {
  u32 u = __float_as_uint(f);
  u = u + 0x7FFFu + ((u >> 16) & 1u);   // round-to-nearest-even
  return (u16)(u >> 16);
}
__device__ __forceinline__ u32 pk(float a, float b) {
  return (u32)f2bf(a) | ((u32)f2bf(b) << 16);
}
__device__ __forceinline__ float lo16(u32 w) { return bf2f(w & 0xFFFFu); }
__device__ __forceinline__ float hi16(u32 w) { return bf2f(w >> 16); }
__device__ __forceinline__ float frcp(float x) { return __builtin_amdgcn_rcpf(x); }
__device__ __forceinline__ float fexp2(float x) { return __builtin_amdgcn_exp2f(x); }  // raw v_exp_f32

#define NL2E   (-1.4426950408889634f)
#define TWOL2E (2.8853900817779268f)
#define CNTSC  1073741824.0            // 2^30: cnt encoded above deg in one double

__device__ __forceinline__ int load_idx(const int* eidx, int is64, long long pos) {
  if (is64) return (int)(((const long long*)eidx)[pos]);
  return eidx[pos];
}

// ---- prep stage 1 (grid 34): WcTmp = Wvl_left @ Wvv, edge-width detect, bc ----
__global__ void k_prep1(const float* Wvl, const float* Wvv,
                        const float* bvv, const float* bvl,
                        const int* eidx, int E, int* flag,
                        float* WcTmp, float* bc) {
  int b = blockIdx.x, tid = threadIdx.x;
  if (b < 32) {
    int c = 2 * b + (tid >> 7), kk = tid & 127;
    float s = 0.f;
    for (int m = 0; m < 64; ++m) s += Wvl[c * 128 + m] * Wvv[m * 128 + kk];
    WcTmp[c * 128 + kk] = s;
  } else if (b == 32) {
    __shared__ int zc;
    if (tid == 0) zc = 0;
    __syncthreads();
    int n = (E < 1024) ? E : 1024;
    int local = 0;
    for (int i = tid; i < n; i += 256) {
      if (eidx[2 * i + 1] == 0) local++;   // high words if int64 (all 0)
    }
    atomicAdd(&zc, local);
    __syncthreads();
    if (tid == 0) *flag = (zc >= (n >> 1)) ? 1 : 0;
  } else if (b == 33) {
    if (tid < 64) {
      float s = 0.f;
      for (int m = 0; m < 64; ++m) s += Wvl[tid * 128 + m] * bvv[m];
      bc[tid] = s + bvl[tid];
    }
  }
}

// ---- prep stage 2 (grid 11) ----
// b0..1: Wsl2 bf16 table; b2: Wpk; b3..10: Wtg split-bf16 W^T for the MFMA GEMM.
// Wtg rows r (u16[512][128], hi at k, lo at 64+k):
//   r<256 (Gs cols): g=r>>6: 0 A_i=Wss_L, 1 C_i=Wsv_L, 2 A_j=Wss_R, 3 C_j=Wsv_R
//   r>=256 (Gv cols): g: 0 B_i=Wvs_L, 1 P_i=Wc_L, 2 B_j=Wvs_R, 3 P_j=Wc_R
__global__ void k_prep2(const float* Wss, const float* Wsv, const float* Wvs,
                        const float* Wsl, const float* Wvl, const float* WcTmp,
                        u32* Wsl2, u32* Wpk, u16* Wtg) {
  int b = blockIdx.x, tid = threadIdx.x;
  if (b < 2) {
    for (int i = 0; i < 8; ++i) {
      int o = b * 2048 + i * 256 + tid;
      int h = o & 1, c = (o >> 1) & 63, g = o >> 7;
      int k = 4 * g + 2 * h;
      Wsl2[o] = pk(Wsl[c * 128 + k], Wsl[c * 128 + k + 1]);
    }
  } else if (b == 2) {
    for (int i = 0; i < 8; ++i) {
      int o = i * 256 + tid;
      int h = o & 1, c = (o >> 1) & 63, g = o >> 7;
      int k = 4 * g + 2 * h;
      Wpk[o] = pk(Wvl[c * 128 + 64 + k], Wvl[c * 128 + 64 + k + 1]);
    }
  } else {
    for (int i = 0; i < 16; ++i) {
      int p = (b - 3) * 4096 + i * 256 + tid;   // 0..32767
      int r = p >> 6, k = p & 63;
      int g = (r >> 6) & 3, ch = r & 63;
      int src = ch * 128 + ((g & 2) ? 64 : 0) + k;
      float w;
      if (r < 256) w = (g & 1) ? Wsv[src] : Wss[src];
      else         w = (g & 1) ? WcTmp[src] : Wvs[src];
      u16 h = f2bf(w);
      Wtg[r * 128 + k] = h;
      Wtg[r * 128 + 64 + k] = f2bf(w - bf2f(h));
    }
  }
}

// one fp64 atomic per edge: dpk[col] += attr + 2^30  (cnt in high part, deg in low)
__global__ void k_deg(const int* eidx, const int* flag, const float* attr,
                      double* dpk, int E) {
  int e = blockIdx.x * 256 + threadIdx.x;
  if (e >= E) return;
  int is64 = *flag;
  int col = load_idx(eidx, is64, (long long)E + e);
  atomicAdd(&dpk[col], (double)attr[e] + CNTSC);
}

// ---- multi-block exclusive scan of cnt -> rowptr, cursor; also emits dis[n] ----
__global__ void k_scan_red(const double* dpk, int* blocksum, float* dis, int N) {
  __shared__ int lds[256];
  int tid = threadIdx.x, idx = blockIdx.x * 256 + tid;
  int c = 0;
  if (idx < N) {
    double p = dpk[idx];
    c = (int)(p * (1.0 / CNTSC));
    float dg = (float)(p - (double)c * CNTSC);
    dis[idx] = (dg > 0.f) ? rsqrtf(dg) : 0.f;
  }
  lds[tid] = c;
  __syncthreads();
  for (int off = 128; off > 0; off >>= 1) {
    if (tid < off) lds[tid] += lds[tid + off];
    __syncthreads();
  }
  if (tid == 0) blocksum[blockIdx.x] = lds[0];
}

__global__ void k_scan_mid(const int* blocksum, int* blockoff, int NB, int* rowptr, int N, int E) {
  __shared__ int lds[1024];
  int tid = threadIdx.x;
  int v = (tid < NB) ? blocksum[tid] : 0;
  lds[tid] = v;
  __syncthreads();
  for (int off = 1; off < 1024; off <<= 1) {
    int t = (tid >= off) ? lds[tid - off] : 0;
    __syncthreads();
    lds[tid] += t;
    __syncthreads();
  }
  if (tid < NB) blockoff[tid] = lds[tid] - v;   // exclusive
  if (tid == 0) rowptr[N] = E;
}

__global__ void k_scan_out(const double* dpk, const int* blockoff, int* rowptr, int* cursor, int N) {
  __shared__ int lds[256];
  int tid = threadIdx.x, idx = blockIdx.x * 256 + tid;
  int v = (idx < N) ? (int)(dpk[idx] * (1.0 / CNTSC)) : 0;
  lds[tid] = v;
  __syncthreads();
  for (int off = 1; off < 256; off <<= 1) {
    int t = (tid >= off) ? lds[tid - off] : 0;
    __syncthreads();
    lds[tid] += t;
    __syncthreads();
  }
  if (idx < N) {
    int o = blockoff[blockIdx.x] + lds[tid] - v;
    rowptr[idx] = o;
    cursor[idx] = o;
  }
}

// CSR fill: erecA[p]={dis_r*attr, dx, dy, dz} (dis[cl] hoisted into k_edges), erecI[p]=row
__global__ void k_fill(const int* eidx, const int* flag, const float* attr, const float* dis,
                       const float* pos, int* cursor, float4* erecA, int* erecI, int E) {
  int e = blockIdx.x * 256 + threadIdx.x;
  if (e >= E) return;
  int is64 = *flag;
  int r  = load_idx(eidx, is64, e);
  int cl = load_idx(eidx, is64, (long long)E + e);
  float wr = dis[r] * attr[e];
  float dx = pos[cl * 3 + 0] - pos[r * 3 + 0];
  float dy = pos[cl * 3 + 1] - pos[r * 3 + 1];
  float dz = pos[cl * 3 + 2] - pos[r * 3 + 2];
  int p = atomicAdd(&cursor[cl], 1);
  erecA[p] = make_float4(wr, dx, dy, dz);
  erecI[p] = r;
}

// ---- MFMA node GEMM (v7) ----
// Block: 512 thr (8 waves), 32 nodes. A-rows (128): [0..31]=scalar, [32+32d..]=v_d.
// A staged in LDS as split-bf16 (hi|lo), XOR-swizzled 16B chunks. B (Wtg) loaded
// per-wave from global into frags. Wave wv owns cols [32wv..32wv+32) of both the
// Gs (rows 0..31) and Gv (rows 32..127) GEMMs. Split product: hi*hi+lo*hi+hi*lo.
// Epilogue: 4 row-group passes via the same 32KB LDS, packing uint4 records.
__global__ __launch_bounds__(512, 4) void k_gemm_rec(
    const float* __restrict__ scalar, const float* __restrict__ vector,
    const u16* __restrict__ Wtg,
    uint4* __restrict__ rec_i4, uint4* __restrict__ rec_j4, int N) {
  __shared__ u32 smem[8192];          // 32 KB: A-tile, then reused as epilogue stage
  u16*   Ax = (u16*)smem;
  float* Ep = (float*)smem;
  int tid = threadIdx.x, lane = tid & 63, wv = tid >> 6;
  int nb = blockIdx.x * 32;

  // ---- stage A: thread t: row = t>>2, 16 k's; convert fp32 -> bf16 hi/lo ----
  {
    int srow = tid >> 2, skq = tid & 3;
    const float* sp;
    int snode;
    if (srow < 32) { snode = nb + srow; sp = scalar + (size_t)snode * 64 + skq * 16; }
    else {
      int d = (srow - 32) >> 5, nl2 = (srow - 32) & 31;
      snode = nb + nl2;
      sp = vector + (size_t)snode * 192 + d * 64 + skq * 16;
    }
    bool valid = snode < N;
    u16 hi[16], lo[16];
    #pragma unroll
    for (int q = 0; q < 4; ++q) {
      float4 v = valid ? *(const float4*)(sp + 4 * q) : make_float4(0.f, 0.f, 0.f, 0.f);
      float xs[4] = {v.x, v.y, v.z, v.w};
      #pragma unroll
      for (int j = 0; j < 4; ++j) {
        u16 h = f2bf(xs[j]);
        hi[4 * q + j] = h;
        lo[4 * q + j] = f2bf(xs[j] - bf2f(h));
      }
    }
    int rs = srow & 7;
    #pragma unroll
    for (int c = 0; c < 2; ++c) {
      int lc = 2 * skq + c;
      uint4 wh, wl;
      wh.x = (u32)hi[8*c+0] | ((u32)hi[8*c+1] << 16);
      wh.y = (u32)hi[8*c+2] | ((u32)hi[8*c+3] << 16);
      wh.z = (u32)hi[8*c+4] | ((u32)hi[8*c+5] << 16);
      wh.w = (u32)hi[8*c+6] | ((u32)hi[8*c+7] << 16);
      wl.x = (u32)lo[8*c+0] | ((u32)lo[8*c+1] << 16);
      wl.y = (u32)lo[8*c+2] | ((u32)lo[8*c+3] << 16);
      wl.z = (u32)lo[8*c+4] | ((u32)lo[8*c+5] << 16);
      wl.w = (u32)lo[8*c+6] | ((u32)lo[8*c+7] << 16);
      *(uint4*)(Ax + srow * 128 + (lc ^ rs) * 8)        = wh;
      *(uint4*)(Ax + srow * 128 + ((8 + lc) ^ rs) * 8)  = wl;
    }
  }
  __syncthreads();

  // ---- MFMA main loop ----
  int c0 = wv * 32;
  int bl = lane & 15, bh = lane >> 4;
  f32x4 acc[8][2];
  #pragma unroll
  for (int mt = 0; mt < 8; ++mt)
    #pragma unroll
    for (int nt = 0; nt < 2; ++nt)
      acc[mt][nt] = (f32x4){0.f, 0.f, 0.f, 0.f};

  #pragma unroll
  for (int kh = 0; kh < 2; ++kh) {
    int k0 = kh * 32;
    bf16x8 Bh[2][2], Bl[2][2];
    #pragma unroll
    for (int rg = 0; rg < 2; ++rg)
      #pragma unroll
      for (int nt = 0; nt < 2; ++nt) {
        size_t rr = (size_t)(rg * 256 + c0 + nt * 16 + bl) * 128 + k0 + bh * 8;
        Bh[rg][nt] = *(const bf16x8*)(Wtg + rr);
        Bl[rg][nt] = *(const bf16x8*)(Wtg + rr + 64);
      }
    #pragma unroll
    for (int mt = 0; mt < 8; ++mt) {
      int row = mt * 16 + bl;
      int ch = (k0 >> 3) + bh, rs = row & 7;
      bf16x8 Ah = *(const bf16x8*)(Ax + row * 128 + (ch ^ rs) * 8);
      bf16x8 Al = *(const bf16x8*)(Ax + row * 128 + ((8 + ch) ^ rs) * 8);
      int rg = (mt < 2) ? 0 : 1;
      #pragma unroll
      for (int nt = 0; nt < 2; ++nt) {
        f32x4 a = acc[mt][nt];
        a = __builtin_amdgcn_mfma_f32_16x16x32_bf16(Ah, Bh[rg][nt], a, 0, 0, 0);
        a = __builtin_amdgcn_mfma_f32_16x16x32_bf16(Al, Bh[rg][nt], a, 0, 0, 0);
        a = __builtin_amdgcn_mfma_f32_16x16x32_bf16(Ah, Bl[rg][nt], a, 0, 0, 0);
        acc[mt][nt] = a;
      }
    }
  }

  // ---- epilogue: 4 passes (Gs, v0, v1, v2) through 32KB stage, pack uint4 ----
  int ech = tid & 63, eng = tid >> 6;
  uint4 oi[4], oj[4];
  #pragma unroll
  for (int pg = 0; pg < 4; ++pg) {
    __syncthreads();
    #pragma unroll
    for (int mm = 0; mm < 2; ++mm) {
      int mt = 2 * pg + mm;
      #pragma unroll
      for (int nt = 0; nt < 2; ++nt)
        #pragma unroll
        for (int r = 0; r < 4; ++r) {
          int rl = mm * 16 + bh * 4 + r;
          Ep[rl * 256 + c0 + nt * 16 + bl] = acc[mt][nt][r];
        }
    }
    __syncthreads();
    #pragma unroll
    for (int q = 0; q < 4; ++q) {
      int nl2 = eng + 8 * q;
      float vi0 = Ep[nl2 * 256 + ech];
      float vi1 = Ep[nl2 * 256 + 64 + ech];
      float vj0 = Ep[nl2 * 256 + 128 + ech];
      float vj1 = Ep[nl2 * 256 + 192 + ech];
      if (pg == 0) {
        oi[q].x = pk(vi0, vi1);                  oj[q].x = pk(vj0, vj1);
      } else if (pg == 1) {
        oi[q].y = (u32)f2bf(vi0);                oj[q].y = (u32)f2bf(vj0);
        oi[q].z = (u32)f2bf(vi1) << 16;          oj[q].z = (u32)f2bf(vj1) << 16;
      } else if (pg == 2) {
        oi[q].y |= (u32)f2bf(vi0) << 16;         oj[q].y |= (u32)f2bf(vj0) << 16;
        oi[q].w = (u32)f2bf(vi1);                oj[q].w = (u32)f2bf(vj1);
      } else {
        oi[q].z |= (u32)f2bf(vi0);               oj[q].z |= (u32)f2bf(vj0);
        oi[q].w |= (u32)f2bf(vi1) << 16;         oj[q].w |= (u32)f2bf(vj1) << 16;
      }
    }
  }
  #pragma unroll
  for (int q = 0; q < 4; ++q) {
    int node = nb + eng + 8 * q;
    if (node < N) {
      rec_i4[(size_t)node * 64 + ech] = oi[q];
      rec_j4[(size_t)node * 64 + ech] = oj[q];
    }
  }
}

// Fused hot kernel: one wave per node, wave-uniform scalar edge metadata,
// 2-edge unrolled loop with double prefetch, in-wave epilogue matvecs.
// All transcendentals via raw v_exp_f32 (log2e folded); dis[cl] hoisted out
// of the per-edge product (accumulators scaled once by disc).
__global__ __launch_bounds__(512) void k_edges(
    const u16* __restrict__ rec_i, const u16* __restrict__ rec_j,
    const float4* __restrict__ erecA, const int* __restrict__ erecI,
    const int* __restrict__ rowptr, const float* __restrict__ dis,
    const float* __restrict__ scalar, const float* __restrict__ vector,
    const float* __restrict__ bss, const float* __restrict__ bvs,
    const float* __restrict__ bsv, const float* __restrict__ bsl,
    const u32* __restrict__ Wsl2g, const u32* __restrict__ Wpkg,
    const float* __restrict__ bcg,
    float* __restrict__ out_s, float* __restrict__ out_v, int N) {
  __shared__ u32 sWsl[4096];        // 16 KB
  __shared__ u32 sWv[2048];         // 8 KB  (Wvl_right only)
  __shared__ float sStage[8 * 128]; // 4 KB, wave-private epilogue stage
  int tid = threadIdx.x, lane = tid & 63, wv = tid >> 6;
  for (int o = tid; o < 4096; o += 512) sWsl[o] = Wsl2g[o];
  for (int o = tid; o < 2048; o += 512) sWv[o] = Wpkg[o];
  __syncthreads();   // the only block barrier

  int node = __builtin_amdgcn_readfirstlane((int)(blockIdx.x * 8) + wv);
  if (node >= N) node = N - 1;

  uint4 riv = *(const uint4*)(rec_i + ((size_t)node << 9) + lane * 8);
  float aiB  = lo16(riv.x) + bss[lane];
  float KciB = TWOL2E * (hi16(riv.x) + bsv[lane]);
  float Bvs  = bvs[lane];
  float bib0 = lo16(riv.y) + Bvs;
  float bib1 = hi16(riv.y) + Bvs;
  float bib2 = lo16(riv.z) + Bvs;
  float Pi0  = hi16(riv.z), Pi1 = lo16(riv.w), Pi2 = hi16(riv.w);
  float bsl_c = bsl[lane], bc_c = bcg[lane];
  float disc = dis[node];

  float us = 0, uv = 0, t0 = 0, t1 = 0, t2 = 0, g0 = 0, g1 = 0, g2 = 0, wa = 0;
  int rp = rowptr[node], re = rowptr[node + 1];
  u32 lane16 = (u32)lane << 4;
  const char* rjb = (const char*)rec_j;

  // erecI has 64 zeroed ints of slack past E -> prefetch reads always valid
  u32 ra = (u32)erecI[rp];
  u32 rb = (u32)erecI[rp + 1];
  uint4 pre0 = *(const uint4*)(rjb + ((ra << 10) + lane16));
  uint4 pre1 = *(const uint4*)(rjb + ((rb << 10) + lane16));
  int p = rp;
  #define EDGE_MATH(CUR, EV)                                                  \
    {                                                                         \
      float nrm = EV.x, dx = EV.y, dy = EV.z, dz = EV.w;                      \
      float aj  = lo16(CUR.x), cj  = hi16(CUR.x);                             \
      float bj0 = lo16(CUR.y), bj1 = hi16(CUR.y), bj2 = lo16(CUR.z);          \
      float rj0 = hi16(CUR.z), rj1 = lo16(CUR.w), rj2 = hi16(CUR.w);          \
      float xs  = aiB + aj;                                                   \
      float s2s = xs * frcp(1.f + fexp2(xs * NL2E));                          \
      float yv  = (bib0 + bj0) * dx;                                          \
      yv = fmaf(bib1 + bj1, dy, yv);                                          \
      yv = fmaf(bib2 + bj2, dz, yv);                                          \
      float v2s = yv * frcp(1.f + fexp2(yv * NL2E));                          \
      float qh  = fmaf(TWOL2E, cj, KciB);                                     \
      float th0 = fmaf(-2.f, frcp(1.f + fexp2(qh * dx)), 1.f);                \
      float th1 = fmaf(-2.f, frcp(1.f + fexp2(qh * dy)), 1.f);                \
      float th2 = fmaf(-2.f, frcp(1.f + fexp2(qh * dz)), 1.f);                \
      us = fmaf(nrm, s2s, us); uv = fmaf(nrm, v2s, uv);                       \
      t0 = fmaf(nrm, th0, t0); t1 = fmaf(nrm, th1, t1); t2 = fmaf(nrm, th2, t2);\
      g0 = fmaf(nrm, rj0, g0); g1 = fmaf(nrm, rj1, g1); g2 = fmaf(nrm, rj2, g2);\
      wa += nrm;                                                              \
    }
  for (; p + 1 < re; p += 2) {
    uint4 cur0 = pre0, cur1 = pre1;
    u32 rn0 = (u32)erecI[p + 2];
    u32 rn1 = (u32)erecI[p + 3];
    pre0 = *(const uint4*)(rjb + ((rn0 << 10) + lane16));
    pre1 = *(const uint4*)(rjb + ((rn1 << 10) + lane16));
    float4 e0 = erecA[p];
    float4 e1 = erecA[p + 1];
    EDGE_MATH(cur0, e0)
    EDGE_MATH(cur1, e1)
  }
  if (p < re) {
    uint4 cur0 = pre0;
    float4 e0 = erecA[p];
    EDGE_MATH(cur0, e0)
  }
  #undef EDGE_MATH

  // scale by the wave-uniform dis[node] (hoisted out of per-edge nrm)
  us *= disc; uv *= disc;
  t0 *= disc; t1 *= disc; t2 *= disc;
  g0 *= disc; g1 *= disc; g2 *= disc;
  wa *= disc;

  // ---- epilogue: scalar head (wave-local, no block barrier) ----
  float* mys = &sStage[wv * 128];
  mys[lane] = us; mys[64 + lane] = uv;
  __threadfence_block();
  float acc = wa * bsl_c;
  #pragma unroll
  for (int g = 0; g < 32; ++g) {
    float4 u = *(const float4*)&mys[4 * g];
    uint2 w = *(const uint2*)&sWsl[(g * 64 + lane) * 2];
    acc = fmaf(u.x, lo16(w.x), acc);
    acc = fmaf(u.y, hi16(w.x), acc);
    acc = fmaf(u.z, lo16(w.y), acc);
    acc = fmaf(u.w, hi16(w.y), acc);
  }
  size_t so = ((size_t)node << 6) + lane;
  out_s[so] = acc * frcp(1.f + fexp2(acc * NL2E)) + scalar[so];

  // ---- epilogue: vector head (t-part matvec only; x,y parts precomputed) ----
  float gg[3] = {g0, g1, g2}, tt[3] = {t0, t1, t2}, Pi[3] = {Pi0, Pi1, Pi2};
  #pragma unroll
  for (int d = 0; d < 3; ++d) {
    size_t vo = (((size_t)node * 3 + d) << 6) + lane;
    float vid = vector[vo];
    __threadfence_block();
    mys[lane] = tt[d];
    __threadfence_block();
    float a2 = fmaf(wa, bc_c + Pi[d], gg[d]);
    #pragma unroll
    for (int g = 0; g < 16; ++g) {
      float4 tu = *(const float4*)&mys[4 * g];
      uint2 w = *(const uint2*)&sWv[(g * 64 + lane) * 2];
      a2 = fmaf(tu.x, lo16(w.x), a2); a2 = fmaf(tu.y, hi16(w.x), a2);
      a2 = fmaf(tu.z, lo16(w.y), a2); a2 = fmaf(tu.w, hi16(w.y), a2);
    }
    float th = fmaf(-2.f, frcp(1.f + fexp2(TWOL2E * a2)), 1.f);
    out_v[vo] = th + vid;
  }
}

extern "C" void kernel_launch(void* const* d_in, const int* in_sizes, int n_in,
                              void* d_out, int out_size, void* d_ws, size_t ws_size,
                              hipStream_t stream) {
  const float* scalar   = (const float*)d_in[0];
  const float* vector   = (const float*)d_in[1];
  const float* position = (const float*)d_in[2];
  const int*   eidx     = (const int*)d_in[3];
  const float* attr     = (const float*)d_in[4];
  const float* Wss = (const float*)d_in[5];
  const float* bss = (const float*)d_in[6];
  const float* Wvs = (const float*)d_in[7];
  const float* bvs = (const float*)d_in[8];
  const float* Wsl = (const float*)d_in[9];
  const float* bsl = (const float*)d_in[10];
  const float* Wsv = (const float*)d_in[11];
  const float* bsv = (const float*)d_in[12];
  const float* Wvv = (const float*)d_in[13];
  const float* bvv = (const float*)d_in[14];
  const float* Wvl = (const float*)d_in[15];
  const float* bvl = (const float*)d_in[16];

  int N = in_sizes[0] / 64;
  int E = in_sizes[4];
  int NB = (N + 255) / 256;   // scan blocks (must be <= 1024)

  char* wsb = (char*)d_ws;
  size_t off = 0;
  auto alloc = [&](size_t bytes) -> char* {
    char* p = wsb + off;
    off += (bytes + 255) & ~(size_t)255;
    return p;
  };
  double* dpk    = (double*)alloc((size_t)N * 8);
  int*    rowptr = (int*)alloc((size_t)(N + 1) * 4);
  int*    cursor = (int*)alloc((size_t)N * 4);
  float*  dis    = (float*)alloc((size_t)N * 4);
  int*    blocksum = (int*)alloc((size_t)NB * 4);
  int*    blockoff = (int*)alloc((size_t)NB * 4);
  float4* erecA  = (float4*)alloc((size_t)E * 16);
  int*    erecI  = (int*)alloc((size_t)(E + 64) * 4);   // +slack for prefetch reads
  u16*    rec_i  = (u16*)alloc((size_t)N * 512 * 2);
  u16*    rec_j  = (u16*)alloc((size_t)N * 512 * 2);
  u16*    Wtg    = (u16*)alloc(512 * 128 * 2);          // 128 KB split-bf16 W^T
  u32*    Wsl2   = (u32*)alloc(4096 * 4);
  u32*    Wpk    = (u32*)alloc(2048 * 4);
  float*  WcTmp  = (float*)alloc(64 * 128 * 4);
  float*  bc     = (float*)alloc(64 * 4);
  int*    flag   = (int*)alloc(4);
  (void)ws_size; (void)n_in; (void)out_size;

  // zero dpk and the erecI prefetch slack
  hipMemsetAsync(dpk, 0, (size_t)((char*)rowptr - (char*)dpk), stream);
  hipMemsetAsync(erecI + E, 0, 64 * 4, stream);

  k_prep1<<<34, 256, 0, stream>>>(Wvl, Wvv, bvv, bvl, eidx, E, flag, WcTmp, bc);
  k_prep2<<<11, 256, 0, stream>>>(Wss, Wsv, Wvs, Wsl, Wvl, WcTmp, Wsl2, Wpk, Wtg);
  k_deg<<<(E + 255) / 256, 256, 0, stream>>>(eidx, flag, attr, dpk, E);
  k_scan_red<<<NB, 256, 0, stream>>>(dpk, blocksum, dis, N);
  k_scan_mid<<<1, 1024, 0, stream>>>(blocksum, blockoff, NB, rowptr, N, E);
  k_scan_out<<<NB, 256, 0, stream>>>(dpk, blockoff, rowptr, cursor, N);
  k_fill<<<(E + 255) / 256, 256, 0, stream>>>(eidx, flag, attr, dis, position, cursor, erecA, erecI, E);
  k_gemm_rec<<<(N + 31) / 32, 512, 0, stream>>>(scalar, vector, Wtg,
                                                (uint4*)rec_i, (uint4*)rec_j, N);
  k_edges<<<(N + 7) / 8, 512, 0, stream>>>(rec_i, rec_j, erecA, erecI, rowptr, dis,
                                           scalar, vector, bss, bvs, bsv, bsl,
                                           Wsl2, Wpk, bc,
                                           (float*)d_out, (float*)d_out + (size_t)N * 64, N);
}

// Round 10
// 405.390 us; speedup vs baseline: 1.5158x; 1.0642x over previous
//
#include <hip/hip_runtime.h>
#include <cstdint>
#include <cstddef>

typedef unsigned int   u32;
typedef unsigned short u16;
typedef __attribute__((ext_vector_type(8))) short bf16x8;
typedef __attribute__((ext_vector_type(4))) float f32x4;

__device__ __forceinline__ float bf2f(u32 bits16) { return __uint_as_float(bits16 << 16); }
__device__ __forceinline__ u16 f2bf(float f) {
  u32 u = __float_as_uint(f);
  u = u + 0x7FFFu + ((u >> 16) & 1u);   // round-to-nearest-even
  return (u16)(u >> 16);
}
__device__ __forceinline__ u32 pk(float a, float b) {
  return (u32)f2bf(a) | ((u32)f2bf(b) << 16);
}
__device__ __forceinline__ float lo16(u32 w) { return bf2f(w & 0xFFFFu); }
__device__ __forceinline__ float hi16(u32 w) { return bf2f(w >> 16); }
__device__ __forceinline__ float frcp(float x) { return __builtin_amdgcn_rcpf(x); }
__device__ __forceinline__ float fexp2(float x) { return __builtin_amdgcn_exp2f(x); }  // raw v_exp_f32

#define NL2E   (-1.4426950408889634f)
#define TWOL2E (2.8853900817779268f)
#define CNTSC  1073741824.0            // 2^30: cnt encoded above deg in one double

__device__ __forceinline__ int load_idx(const int* eidx, int is64, long long pos) {
  if (is64) return (int)(((const long long*)eidx)[pos]);
  return eidx[pos];
}

// ---- prep stage 1 (grid 35 + ceil(N/256)) ----
// b<32: WcTmp = Wvl_left @ Wvv   b32: edge-width detect   b33: bc
// b34: zero erecI prefetch slack   b>=35: zero dpk
__global__ void k_prep1(const float* Wvl, const float* Wvv,
                        const float* bvv, const float* bvl,
                        const int* eidx, int E, int* flag,
                        float* WcTmp, float* bc,
                        double* dpk, int* erecI, int N) {
  int b = blockIdx.x, tid = threadIdx.x;
  if (b < 32) {
    int c = 2 * b + (tid >> 7), kk = tid & 127;
    float s = 0.f;
    for (int m = 0; m < 64; ++m) s += Wvl[c * 128 + m] * Wvv[m * 128 + kk];
    WcTmp[c * 128 + kk] = s;
  } else if (b == 32) {
    __shared__ int zc;
    if (tid == 0) zc = 0;
    __syncthreads();
    int n = (E < 1024) ? E : 1024;
    int local = 0;
    for (int i = tid; i < n; i += 256) {
      if (eidx[2 * i + 1] == 0) local++;   // high words if int64 (all 0)
    }
    atomicAdd(&zc, local);
    __syncthreads();
    if (tid == 0) *flag = (zc >= (n >> 1)) ? 1 : 0;
  } else if (b == 33) {
    if (tid < 64) {
      float s = 0.f;
      for (int m = 0; m < 64; ++m) s += Wvl[tid * 128 + m] * bvv[m];
      bc[tid] = s + bvl[tid];
    }
  } else if (b == 34) {
    if (tid < 64) erecI[E + tid] = 0;
  } else {
    int idx = (b - 35) * 256 + tid;
    if (idx < N) dpk[idx] = 0.0;
  }
}

// ---- prep stage 2 (grid 11) ----
// b0..1: Wsl2 bf16 table; b2: Wpk; b3..10: Wtg split-bf16 W^T for the MFMA GEMM.
// Wtg rows r (u16[512][128], hi at k, lo at 64+k):
//   r<256 (Gs cols): g=r>>6: 0 A_i=Wss_L, 1 C_i=Wsv_L, 2 A_j=Wss_R, 3 C_j=Wsv_R
//   r>=256 (Gv cols): g: 0 B_i=Wvs_L, 1 P_i=Wc_L, 2 B_j=Wvs_R, 3 P_j=Wc_R
__global__ void k_prep2(const float* Wss, const float* Wsv, const float* Wvs,
                        const float* Wsl, const float* Wvl, const float* WcTmp,
                        u32* Wsl2, u32* Wpk, u16* Wtg) {
  int b = blockIdx.x, tid = threadIdx.x;
  if (b < 2) {
    for (int i = 0; i < 8; ++i) {
      int o = b * 2048 + i * 256 + tid;
      int h = o & 1, c = (o >> 1) & 63, g = o >> 7;
      int k = 4 * g + 2 * h;
      Wsl2[o] = pk(Wsl[c * 128 + k], Wsl[c * 128 + k + 1]);
    }
  } else if (b == 2) {
    for (int i = 0; i < 8; ++i) {
      int o = i * 256 + tid;
      int h = o & 1, c = (o >> 1) & 63, g = o >> 7;
      int k = 4 * g + 2 * h;
      Wpk[o] = pk(Wvl[c * 128 + 64 + k], Wvl[c * 128 + 64 + k + 1]);
    }
  } else {
    for (int i = 0; i < 16; ++i) {
      int p = (b - 3) * 4096 + i * 256 + tid;   // 0..32767
      int r = p >> 6, k = p & 63;
      int g = (r >> 6) & 3, ch = r & 63;
      int src = ch * 128 + ((g & 2) ? 64 : 0) + k;
      float w;
      if (r < 256) w = (g & 1) ? Wsv[src] : Wss[src];
      else         w = (g & 1) ? WcTmp[src] : Wvs[src];
      u16 h = f2bf(w);
      Wtg[r * 128 + k] = h;
      Wtg[r * 128 + 64 + k] = f2bf(w - bf2f(h));
    }
  }
}

// ---- multi-block exclusive scan of cnt -> rowptr, cursor; also emits dis[n] ----
__global__ void k_scan_red(const double* dpk, int* blocksum, float* dis, int N) {
  __shared__ int lds[256];
  int tid = threadIdx.x, idx = blockIdx.x * 256 + tid;
  int c = 0;
  if (idx < N) {
    double p = dpk[idx];
    c = (int)(p * (1.0 / CNTSC));
    float dg = (float)(p - (double)c * CNTSC);
    dis[idx] = (dg > 0.f) ? rsqrtf(dg) : 0.f;
  }
  lds[tid] = c;
  __syncthreads();
  for (int off = 128; off > 0; off >>= 1) {
    if (tid < off) lds[tid] += lds[tid + off];
    __syncthreads();
  }
  if (tid == 0) blocksum[blockIdx.x] = lds[0];
}

__global__ void k_scan_mid(const int* blocksum, int* blockoff, int NB, int* rowptr, int N, int E) {
  __shared__ int lds[1024];
  int tid = threadIdx.x;
  int v = (tid < NB) ? blocksum[tid] : 0;
  lds[tid] = v;
  __syncthreads();
  for (int off = 1; off < 1024; off <<= 1) {
    int t = (tid >= off) ? lds[tid - off] : 0;
    __syncthreads();
    lds[tid] += t;
    __syncthreads();
  }
  if (tid < NB) blockoff[tid] = lds[tid] - v;   // exclusive
  if (tid == 0) rowptr[N] = E;
}

__global__ void k_scan_out(const double* dpk, const int* blockoff, int* rowptr, int* cursor, int N) {
  __shared__ int lds[256];
  int tid = threadIdx.x, idx = blockIdx.x * 256 + tid;
  int v = (idx < N) ? (int)(dpk[idx] * (1.0 / CNTSC)) : 0;
  lds[tid] = v;
  __syncthreads();
  for (int off = 1; off < 256; off <<= 1) {
    int t = (tid >= off) ? lds[tid - off] : 0;
    __syncthreads();
    lds[tid] += t;
    __syncthreads();
  }
  if (idx < N) {
    int o = blockoff[blockIdx.x] + lds[tid] - v;
    rowptr[idx] = o;
    cursor[idx] = o;
  }
}

// CSR fill: erecA[p]={dis_r*attr, dx, dy, dz} (dis[cl] hoisted into k_edges), erecI[p]=row
__global__ void k_fill(const int* eidx, const int* flag, const float* attr, const float* dis,
                       const float* pos, int* cursor, float4* erecA, int* erecI, int E) {
  int e = blockIdx.x * 256 + threadIdx.x;
  if (e >= E) return;
  int is64 = *flag;
  int r  = load_idx(eidx, is64, e);
  int cl = load_idx(eidx, is64, (long long)E + e);
  float wr = dis[r] * attr[e];
  float dx = pos[cl * 3 + 0] - pos[r * 3 + 0];
  float dy = pos[cl * 3 + 1] - pos[r * 3 + 1];
  float dz = pos[cl * 3 + 2] - pos[r * 3 + 2];
  int p = atomicAdd(&cursor[cl], 1);
  erecA[p] = make_float4(wr, dx, dy, dz);
  erecI[p] = r;
}

// ---- fused MFMA node GEMM + degree atomics (independent work co-scheduled) ----
// blocks [0,GB): gemm v7 (512 thr, 32 nodes, split-bf16 MFMA, see r7 notes)
// blocks [GB,GB+DB): k_deg (one fp64 atomic per edge: dpk[col] += attr + 2^30)
__global__ __launch_bounds__(512, 4) void k_gemm_deg(
    const float* __restrict__ scalar, const float* __restrict__ vector,
    const u16* __restrict__ Wtg,
    uint4* __restrict__ rec_i4, uint4* __restrict__ rec_j4, int N, int GB,
    const int* __restrict__ eidx, const int* __restrict__ flag,
    const float* __restrict__ attr, double* __restrict__ dpk, int E) {
  __shared__ u32 smem[8192];          // 32 KB: A-tile, then reused as epilogue stage
  int tid = threadIdx.x;
  if ((int)blockIdx.x >= GB) {
    int e = ((int)blockIdx.x - GB) * 512 + tid;
    if (e < E) {
      int is64 = *flag;
      int col = load_idx(eidx, is64, (long long)E + e);
      atomicAdd(&dpk[col], (double)attr[e] + CNTSC);
    }
    return;
  }
  u16*   Ax = (u16*)smem;
  float* Ep = (float*)smem;
  int lane = tid & 63, wv = tid >> 6;
  int nb = blockIdx.x * 32;

  // ---- stage A: thread t: row = t>>2, 16 k's; convert fp32 -> bf16 hi/lo ----
  {
    int srow = tid >> 2, skq = tid & 3;
    const float* sp;
    int snode;
    if (srow < 32) { snode = nb + srow; sp = scalar + (size_t)snode * 64 + skq * 16; }
    else {
      int d = (srow - 32) >> 5, nl2 = (srow - 32) & 31;
      snode = nb + nl2;
      sp = vector + (size_t)snode * 192 + d * 64 + skq * 16;
    }
    bool valid = snode < N;
    u16 hi[16], lo[16];
    #pragma unroll
    for (int q = 0; q < 4; ++q) {
      float4 v = valid ? *(const float4*)(sp + 4 * q) : make_float4(0.f, 0.f, 0.f, 0.f);
      float xs[4] = {v.x, v.y, v.z, v.w};
      #pragma unroll
      for (int j = 0; j < 4; ++j) {
        u16 h = f2bf(xs[j]);
        hi[4 * q + j] = h;
        lo[4 * q + j] = f2bf(xs[j] - bf2f(h));
      }
    }
    int rs = srow & 7;
    #pragma unroll
    for (int c = 0; c < 2; ++c) {
      int lc = 2 * skq + c;
      uint4 wh, wl;
      wh.x = (u32)hi[8*c+0] | ((u32)hi[8*c+1] << 16);
      wh.y = (u32)hi[8*c+2] | ((u32)hi[8*c+3] << 16);
      wh.z = (u32)hi[8*c+4] | ((u32)hi[8*c+5] << 16);
      wh.w = (u32)hi[8*c+6] | ((u32)hi[8*c+7] << 16);
      wl.x = (u32)lo[8*c+0] | ((u32)lo[8*c+1] << 16);
      wl.y = (u32)lo[8*c+2] | ((u32)lo[8*c+3] << 16);
      wl.z = (u32)lo[8*c+4] | ((u32)lo[8*c+5] << 16);
      wl.w = (u32)lo[8*c+6] | ((u32)lo[8*c+7] << 16);
      *(uint4*)(Ax + srow * 128 + (lc ^ rs) * 8)        = wh;
      *(uint4*)(Ax + srow * 128 + ((8 + lc) ^ rs) * 8)  = wl;
    }
  }
  __syncthreads();

  // ---- MFMA main loop ----
  int c0 = wv * 32;
  int bl = lane & 15, bh = lane >> 4;
  f32x4 acc[8][2];
  #pragma unroll
  for (int mt = 0; mt < 8; ++mt)
    #pragma unroll
    for (int nt = 0; nt < 2; ++nt)
      acc[mt][nt] = (f32x4){0.f, 0.f, 0.f, 0.f};

  #pragma unroll
  for (int kh = 0; kh < 2; ++kh) {
    int k0 = kh * 32;
    bf16x8 Bh[2][2], Bl[2][2];
    #pragma unroll
    for (int rg = 0; rg < 2; ++rg)
      #pragma unroll
      for (int nt = 0; nt < 2; ++nt) {
        size_t rr = (size_t)(rg * 256 + c0 + nt * 16 + bl) * 128 + k0 + bh * 8;
        Bh[rg][nt] = *(const bf16x8*)(Wtg + rr);
        Bl[rg][nt] = *(const bf16x8*)(Wtg + rr + 64);
      }
    #pragma unroll
    for (int mt = 0; mt < 8; ++mt) {
      int row = mt * 16 + bl;
      int ch = (k0 >> 3) + bh, rs = row & 7;
      bf16x8 Ah = *(const bf16x8*)(Ax + row * 128 + (ch ^ rs) * 8);
      bf16x8 Al = *(const bf16x8*)(Ax + row * 128 + ((8 + ch) ^ rs) * 8);
      int rg = (mt < 2) ? 0 : 1;
      #pragma unroll
      for (int nt = 0; nt < 2; ++nt) {
        f32x4 a = acc[mt][nt];
        a = __builtin_amdgcn_mfma_f32_16x16x32_bf16(Ah, Bh[rg][nt], a, 0, 0, 0);
        a = __builtin_amdgcn_mfma_f32_16x16x32_bf16(Al, Bh[rg][nt], a, 0, 0, 0);
        a = __builtin_amdgcn_mfma_f32_16x16x32_bf16(Ah, Bl[rg][nt], a, 0, 0, 0);
        acc[mt][nt] = a;
      }
    }
  }

  // ---- epilogue: 4 passes (Gs, v0, v1, v2) through 32KB stage, pack uint4 ----
  int ech = tid & 63, eng = tid >> 6;
  uint4 oi[4], oj[4];
  #pragma unroll
  for (int pg = 0; pg < 4; ++pg) {
    __syncthreads();
    #pragma unroll
    for (int mm = 0; mm < 2; ++mm) {
      int mt = 2 * pg + mm;
      #pragma unroll
      for (int nt = 0; nt < 2; ++nt)
        #pragma unroll
        for (int r = 0; r < 4; ++r) {
          int rl = mm * 16 + bh * 4 + r;
          Ep[rl * 256 + c0 + nt * 16 + bl] = acc[mt][nt][r];
        }
    }
    __syncthreads();
    #pragma unroll
    for (int q = 0; q < 4; ++q) {
      int nl2 = eng + 8 * q;
      float vi0 = Ep[nl2 * 256 + ech];
      float vi1 = Ep[nl2 * 256 + 64 + ech];
      float vj0 = Ep[nl2 * 256 + 128 + ech];
      float vj1 = Ep[nl2 * 256 + 192 + ech];
      if (pg == 0) {
        oi[q].x = pk(vi0, vi1);                  oj[q].x = pk(vj0, vj1);
      } else if (pg == 1) {
        oi[q].y = (u32)f2bf(vi0);                oj[q].y = (u32)f2bf(vj0);
        oi[q].z = (u32)f2bf(vi1) << 16;          oj[q].z = (u32)f2bf(vj1) << 16;
      } else if (pg == 2) {
        oi[q].y |= (u32)f2bf(vi0) << 16;         oj[q].y |= (u32)f2bf(vj0) << 16;
        oi[q].w = (u32)f2bf(vi1);                oj[q].w = (u32)f2bf(vj1);
      } else {
        oi[q].z |= (u32)f2bf(vi0);               oj[q].z |= (u32)f2bf(vj0);
        oi[q].w |= (u32)f2bf(vi1) << 16;         oj[q].w |= (u32)f2bf(vj1) << 16;
      }
    }
  }
  #pragma unroll
  for (int q = 0; q < 4; ++q) {
    int node = nb + eng + 8 * q;
    if (node < N) {
      rec_i4[(size_t)node * 64 + ech] = oi[q];
      rec_j4[(size_t)node * 64 + ech] = oj[q];
    }
  }
}

// Fused hot kernel: one wave per node, wave-uniform scalar edge metadata,
// 2-edge unrolled loop with double prefetch, in-wave epilogue matvecs.
// All transcendentals via raw v_exp_f32 (log2e folded); dis[cl] hoisted out
// of the per-edge product (accumulators scaled once by disc).
__global__ __launch_bounds__(512) void k_edges(
    const u16* __restrict__ rec_i, const u16* __restrict__ rec_j,
    const float4* __restrict__ erecA, const int* __restrict__ erecI,
    const int* __restrict__ rowptr, const float* __restrict__ dis,
    const float* __restrict__ scalar, const float* __restrict__ vector,
    const float* __restrict__ bss, const float* __restrict__ bvs,
    const float* __restrict__ bsv, const float* __restrict__ bsl,
    const u32* __restrict__ Wsl2g, const u32* __restrict__ Wpkg,
    const float* __restrict__ bcg,
    float* __restrict__ out_s, float* __restrict__ out_v, int N) {
  __shared__ u32 sWsl[4096];        // 16 KB
  __shared__ u32 sWv[2048];         // 8 KB  (Wvl_right only)
  __shared__ float sStage[8 * 128]; // 4 KB, wave-private epilogue stage
  int tid = threadIdx.x, lane = tid & 63, wv = tid >> 6;
  for (int o = tid; o < 4096; o += 512) sWsl[o] = Wsl2g[o];
  for (int o = tid; o < 2048; o += 512) sWv[o] = Wpkg[o];
  __syncthreads();   // the only block barrier

  int node = __builtin_amdgcn_readfirstlane((int)(blockIdx.x * 8) + wv);
  if (node >= N) node = N - 1;

  uint4 riv = *(const uint4*)(rec_i + ((size_t)node << 9) + lane * 8);
  float aiB  = lo16(riv.x) + bss[lane];
  float KciB = TWOL2E * (hi16(riv.x) + bsv[lane]);
  float Bvs  = bvs[lane];
  float bib0 = lo16(riv.y) + Bvs;
  float bib1 = hi16(riv.y) + Bvs;
  float bib2 = lo16(riv.z) + Bvs;
  float Pi0  = hi16(riv.z), Pi1 = lo16(riv.w), Pi2 = hi16(riv.w);
  float bsl_c = bsl[lane], bc_c = bcg[lane];
  float disc = dis[node];

  float us = 0, uv = 0, t0 = 0, t1 = 0, t2 = 0, g0 = 0, g1 = 0, g2 = 0, wa = 0;
  int rp = rowptr[node], re = rowptr[node + 1];
  u32 lane16 = (u32)lane << 4;
  const char* rjb = (const char*)rec_j;

  // erecI has 64 zeroed ints of slack past E -> prefetch reads always valid
  u32 ra = (u32)erecI[rp];
  u32 rb = (u32)erecI[rp + 1];
  uint4 pre0 = *(const uint4*)(rjb + ((ra << 10) + lane16));
  uint4 pre1 = *(const uint4*)(rjb + ((rb << 10) + lane16));
  int p = rp;
  #define EDGE_MATH(CUR, EV)                                                  \
    {                                                                         \
      float nrm = EV.x, dx = EV.y, dy = EV.z, dz = EV.w;                      \
      float aj  = lo16(CUR.x), cj  = hi16(CUR.x);                             \
      float bj0 = lo16(CUR.y), bj1 = hi16(CUR.y), bj2 = lo16(CUR.z);          \
      float rj0 = hi16(CUR.z), rj1 = lo16(CUR.w), rj2 = hi16(CUR.w);          \
      float xs  = aiB + aj;                                                   \
      float s2s = xs * frcp(1.f + fexp2(xs * NL2E));                          \
      float yv  = (bib0 + bj0) * dx;                                          \
      yv = fmaf(bib1 + bj1, dy, yv);                                          \
      yv = fmaf(bib2 + bj2, dz, yv);                                          \
      float v2s = yv * frcp(1.f + fexp2(yv * NL2E));                          \
      float qh  = fmaf(TWOL2E, cj, KciB);                                     \
      float th0 = fmaf(-2.f, frcp(1.f + fexp2(qh * dx)), 1.f);                \
      float th1 = fmaf(-2.f, frcp(1.f + fexp2(qh * dy)), 1.f);                \
      float th2 = fmaf(-2.f, frcp(1.f + fexp2(qh * dz)), 1.f);                \
      us = fmaf(nrm, s2s, us); uv = fmaf(nrm, v2s, uv);                       \
      t0 = fmaf(nrm, th0, t0); t1 = fmaf(nrm, th1, t1); t2 = fmaf(nrm, th2, t2);\
      g0 = fmaf(nrm, rj0, g0); g1 = fmaf(nrm, rj1, g1); g2 = fmaf(nrm, rj2, g2);\
      wa += nrm;                                                              \
    }
  for (; p + 1 < re; p += 2) {
    uint4 cur0 = pre0, cur1 = pre1;
    u32 rn0 = (u32)erecI[p + 2];
    u32 rn1 = (u32)erecI[p + 3];
    pre0 = *(const uint4*)(rjb + ((rn0 << 10) + lane16));
    pre1 = *(const uint4*)(rjb + ((rn1 << 10) + lane16));
    float4 e0 = erecA[p];
    float4 e1 = erecA[p + 1];
    EDGE_MATH(cur0, e0)
    EDGE_MATH(cur1, e1)
  }
  if (p < re) {
    uint4 cur0 = pre0;
    float4 e0 = erecA[p];
    EDGE_MATH(cur0, e0)
  }
  #undef EDGE_MATH

  // scale by the wave-uniform dis[node] (hoisted out of per-edge nrm)
  us *= disc; uv *= disc;
  t0 *= disc; t1 *= disc; t2 *= disc;
  g0 *= disc; g1 *= disc; g2 *= disc;
  wa *= disc;

  // ---- epilogue: scalar head (wave-local, no block barrier) ----
  float* mys = &sStage[wv * 128];
  mys[lane] = us; mys[64 + lane] = uv;
  __threadfence_block();
  float acc = wa * bsl_c;
  #pragma unroll
  for (int g = 0; g < 32; ++g) {
    float4 u = *(const float4*)&mys[4 * g];
    uint2 w = *(const uint2*)&sWsl[(g * 64 + lane) * 2];
    acc = fmaf(u.x, lo16(w.x), acc);
    acc = fmaf(u.y, hi16(w.x), acc);
    acc = fmaf(u.z, lo16(w.y), acc);
    acc = fmaf(u.w, hi16(w.y), acc);
  }
  size_t so = ((size_t)node << 6) + lane;
  out_s[so] = acc * frcp(1.f + fexp2(acc * NL2E)) + scalar[so];

  // ---- epilogue: vector head (t-part matvec only; x,y parts precomputed) ----
  float gg[3] = {g0, g1, g2}, tt[3] = {t0, t1, t2}, Pi[3] = {Pi0, Pi1, Pi2};
  #pragma unroll
  for (int d = 0; d < 3; ++d) {
    size_t vo = (((size_t)node * 3 + d) << 6) + lane;
    float vid = vector[vo];
    __threadfence_block();
    mys[lane] = tt[d];
    __threadfence_block();
    float a2 = fmaf(wa, bc_c + Pi[d], gg[d]);
    #pragma unroll
    for (int g = 0; g < 16; ++g) {
      float4 tu = *(const float4*)&mys[4 * g];
      uint2 w = *(const uint2*)&sWv[(g * 64 + lane) * 2];
      a2 = fmaf(tu.x, lo16(w.x), a2); a2 = fmaf(tu.y, hi16(w.x), a2);
      a2 = fmaf(tu.z, lo16(w.y), a2); a2 = fmaf(tu.w, hi16(w.y), a2);
    }
    float th = fmaf(-2.f, frcp(1.f + fexp2(TWOL2E * a2)), 1.f);
    out_v[vo] = th + vid;
  }
}

extern "C" void kernel_launch(void* const* d_in, const int* in_sizes, int n_in,
                              void* d_out, int out_size, void* d_ws, size_t ws_size,
                              hipStream_t stream) {
  const float* scalar   = (const float*)d_in[0];
  const float* vector   = (const float*)d_in[1];
  const float* position = (const float*)d_in[2];
  const int*   eidx     = (const int*)d_in[3];
  const float* attr     = (const float*)d_in[4];
  const float* Wss = (const float*)d_in[5];
  const float* bss = (const float*)d_in[6];
  const float* Wvs = (const float*)d_in[7];
  const float* bvs = (const float*)d_in[8];
  const float* Wsl = (const float*)d_in[9];
  const float* bsl = (const float*)d_in[10];
  const float* Wsv = (const float*)d_in[11];
  const float* bsv = (const float*)d_in[12];
  const float* Wvv = (const float*)d_in[13];
  const float* bvv = (const float*)d_in[14];
  const float* Wvl = (const float*)d_in[15];
  const float* bvl = (const float*)d_in[16];

  int N = in_sizes[0] / 64;
  int E = in_sizes[4];
  int NB = (N + 255) / 256;   // scan blocks (must be <= 1024)

  char* wsb = (char*)d_ws;
  size_t off = 0;
  auto alloc = [&](size_t bytes) -> char* {
    char* p = wsb + off;
    off += (bytes + 255) & ~(size_t)255;
    return p;
  };
  double* dpk    = (double*)alloc((size_t)N * 8);
  int*    rowptr = (int*)alloc((size_t)(N + 1) * 4);
  int*    cursor = (int*)alloc((size_t)N * 4);
  float*  dis    = (float*)alloc((size_t)N * 4);
  int*    blocksum = (int*)alloc((size_t)NB * 4);
  int*    blockoff = (int*)alloc((size_t)NB * 4);
  float4* erecA  = (float4*)alloc((size_t)E * 16);
  int*    erecI  = (int*)alloc((size_t)(E + 64) * 4);   // +slack for prefetch reads
  u16*    rec_i  = (u16*)alloc((size_t)N * 512 * 2);
  u16*    rec_j  = (u16*)alloc((size_t)N * 512 * 2);
  u16*    Wtg    = (u16*)alloc(512 * 128 * 2);          // 128 KB split-bf16 W^T
  u32*    Wsl2   = (u32*)alloc(4096 * 4);
  u32*    Wpk    = (u32*)alloc(2048 * 4);
  float*  WcTmp  = (float*)alloc(64 * 128 * 4);
  float*  bc     = (float*)alloc(64 * 4);
  int*    flag   = (int*)alloc(4);
  (void)ws_size; (void)n_in; (void)out_size;

  int GB = (N + 31) / 32;     // gemm blocks
  int DB = (E + 511) / 512;   // deg blocks

  k_prep1<<<35 + NB, 256, 0, stream>>>(Wvl, Wvv, bvv, bvl, eidx, E, flag,
                                       WcTmp, bc, dpk, erecI, N);
  k_prep2<<<11, 256, 0, stream>>>(Wss, Wsv, Wvs, Wsl, Wvl, WcTmp, Wsl2, Wpk, Wtg);
  k_gemm_deg<<<GB + DB, 512, 0, stream>>>(scalar, vector, Wtg,
                                          (uint4*)rec_i, (uint4*)rec_j, N, GB,
                                          eidx, flag, attr, dpk, E);
  k_scan_red<<<NB, 256, 0, stream>>>(dpk, blocksum, dis, N);
  k_scan_mid<<<1, 1024, 0, stream>>>(blocksum, blockoff, NB, rowptr, N, E);
  k_scan_out<<<NB, 256, 0, stream>>>(dpk, blockoff, rowptr, cursor, N);
  k_fill<<<(E + 255) / 256, 256, 0, stream>>>(eidx, flag, attr, dis, position, cursor, erecA, erecI, E);
  k_edges<<<(N + 7) / 8, 512, 0, stream>>>(rec_i, rec_j, erecA, erecI, rowptr, dis,
                                           scalar, vector, bss, bvs, bsv, bsl,
                                           Wsl2, Wpk, bc,
                                           (float*)d_out, (float*)d_out + (size_t)N * 64, N);
}

// Round 11
// 404.456 us; speedup vs baseline: 1.5193x; 1.0023x over previous
//
#include <hip/hip_runtime.h>
#include <cstdint>
#include <cstddef>

typedef unsigned int   u32;
typedef unsigned short u16;
typedef __attribute__((ext_vector_type(8))) short bf16x8;
typedef __attribute__((ext_vector_type(4))) float f32x4;

__device__ __forceinline__ float bf2f(u32 bits16) { return __uint_as_float(bits16 << 16); }
__device__ __forceinline__ u16 f2bf(float f) {
  u32 u = __float_as_uint(f);
  u = u + 0x7FFFu + ((u >> 16) & 1u);   // round-to-nearest-even
  return (u16)(u >> 16);
}
__device__ __forceinline__ u32 pk(float a, float b) {
  return (u32)f2bf(a) | ((u32)f2bf(b) << 16);
}
__device__ __forceinline__ float lo16(u32 w) { return bf2f(w & 0xFFFFu); }
__device__ __forceinline__ float hi16(u32 w) { return bf2f(w >> 16); }
__device__ __forceinline__ float frcp(float x) { return __builtin_amdgcn_rcpf(x); }
__device__ __forceinline__ float fexp2(float x) { return __builtin_amdgcn_exp2f(x); }  // raw v_exp_f32

#define NL2E   (-1.4426950408889634f)
#define TWOL2E (2.8853900817779268f)
#define CNTSC  1073741824.0            // 2^30: cnt encoded above deg in one double

__device__ __forceinline__ int load_idx(const int* eidx, int is64, long long pos) {
  if (is64) return (int)(((const long long*)eidx)[pos]);
  return eidx[pos];
}

// ---- prep stage 1 (grid 35 + ceil(N/256)) ----
// b<32: WcTmp = Wvl_left @ Wvv   b32: edge-width detect   b33: bc
// b34: zero erecI slack + scan tilestat/tilectr   b>=35: zero dpk
__global__ void k_prep1(const float* Wvl, const float* Wvv,
                        const float* bvv, const float* bvl,
                        const int* eidx, int E, int* flag,
                        float* WcTmp, float* bc,
                        double* dpk, int* erecI, int* tilestat, int* tilectr,
                        int N, int NB) {
  int b = blockIdx.x, tid = threadIdx.x;
  if (b < 32) {
    int c = 2 * b + (tid >> 7), kk = tid & 127;
    float s = 0.f;
    for (int m = 0; m < 64; ++m) s += Wvl[c * 128 + m] * Wvv[m * 128 + kk];
    WcTmp[c * 128 + kk] = s;
  } else if (b == 32) {
    __shared__ int zc;
    if (tid == 0) zc = 0;
    __syncthreads();
    int n = (E < 1024) ? E : 1024;
    int local = 0;
    for (int i = tid; i < n; i += 256) {
      if (eidx[2 * i + 1] == 0) local++;   // high words if int64 (all 0)
    }
    atomicAdd(&zc, local);
    __syncthreads();
    if (tid == 0) *flag = (zc >= (n >> 1)) ? 1 : 0;
  } else if (b == 33) {
    if (tid < 64) {
      float s = 0.f;
      for (int m = 0; m < 64; ++m) s += Wvl[tid * 128 + m] * bvv[m];
      bc[tid] = s + bvl[tid];
    }
  } else if (b == 34) {
    if (tid < 64) erecI[E + tid] = 0;
    if (tid == 64) *tilectr = 0;
    for (int i = tid; i < NB; i += 256) tilestat[i] = 0;
  } else {
    int idx = (b - 35) * 256 + tid;
    if (idx < N) dpk[idx] = 0.0;
  }
}

// ---- prep stage 2 (grid 11) ----
// b0..1: Wsl2 bf16 table; b2: Wpk; b3..10: Wtg split-bf16 W^T for the MFMA GEMM.
// Wtg rows r (u16[512][128], hi at k, lo at 64+k):
//   r<256 (Gs cols): g=r>>6: 0 A_i=Wss_L, 1 C_i=Wsv_L, 2 A_j=Wss_R, 3 C_j=Wsv_R
//   r>=256 (Gv cols): g: 0 B_i=Wvs_L, 1 P_i=Wc_L, 2 B_j=Wvs_R, 3 P_j=Wc_R
__global__ void k_prep2(const float* Wss, const float* Wsv, const float* Wvs,
                        const float* Wsl, const float* Wvl, const float* WcTmp,
                        u32* Wsl2, u32* Wpk, u16* Wtg) {
  int b = blockIdx.x, tid = threadIdx.x;
  if (b < 2) {
    for (int i = 0; i < 8; ++i) {
      int o = b * 2048 + i * 256 + tid;
      int h = o & 1, c = (o >> 1) & 63, g = o >> 7;
      int k = 4 * g + 2 * h;
      Wsl2[o] = pk(Wsl[c * 128 + k], Wsl[c * 128 + k + 1]);
    }
  } else if (b == 2) {
    for (int i = 0; i < 8; ++i) {
      int o = i * 256 + tid;
      int h = o & 1, c = (o >> 1) & 63, g = o >> 7;
      int k = 4 * g + 2 * h;
      Wpk[o] = pk(Wvl[c * 128 + 64 + k], Wvl[c * 128 + 64 + k + 1]);
    }
  } else {
    for (int i = 0; i < 16; ++i) {
      int p = (b - 3) * 4096 + i * 256 + tid;   // 0..32767
      int r = p >> 6, k = p & 63;
      int g = (r >> 6) & 3, ch = r & 63;
      int src = ch * 128 + ((g & 2) ? 64 : 0) + k;
      float w;
      if (r < 256) w = (g & 1) ? Wsv[src] : Wss[src];
      else         w = (g & 1) ? WcTmp[src] : Wvs[src];
      u16 h = f2bf(w);
      Wtg[r * 128 + k] = h;
      Wtg[r * 128 + 64 + k] = f2bf(w - bf2f(h));
    }
  }
}

// ---- single-pass decoupled-lookback scan: dpk -> rowptr, cursor, dis ----
// tilestat[t] packs (flag<<30)|value, value<2^30 (E<2^30): flag 1=aggregate, 2=prefix.
__global__ void k_scan(const double* dpk, float* dis, int* rowptr, int* cursor,
                       int* tilestat, int* tilectr, int N, int E) {
  __shared__ int lds[256];
  __shared__ int sTile, sPrefix;
  int tid = threadIdx.x;
  if (tid == 0) sTile = atomicAdd(tilectr, 1);
  __syncthreads();
  int tile = sTile;
  int idx = tile * 256 + tid;
  int c = 0;
  if (idx < N) {
    double p = dpk[idx];
    c = (int)(p * (1.0 / CNTSC));
    float dg = (float)(p - (double)c * CNTSC);
    dis[idx] = (dg > 0.f) ? rsqrtf(dg) : 0.f;
  }
  lds[tid] = c;
  __syncthreads();
  for (int off = 1; off < 256; off <<= 1) {
    int t = (tid >= off) ? lds[tid - off] : 0;
    __syncthreads();
    lds[tid] += t;
    __syncthreads();
  }
  int incl = lds[tid];
  int aggregate = lds[255];
  if (tid == 0) {
    if (tile == 0) {
      atomicExch(&tilestat[0], (2 << 30) | aggregate);
      rowptr[N] = E;
    } else {
      atomicExch(&tilestat[tile], (1 << 30) | aggregate);
      int excl = 0;
      int t = tile - 1;
      while (true) {
        int s = atomicAdd(&tilestat[t], 0);
        int flag = (u32)s >> 30;
        if (flag == 0) continue;   // spin: predecessor not published yet
        excl += s & 0x3FFFFFFF;
        if (flag == 2) break;
        --t;
      }
      sPrefix = excl;
      atomicExch(&tilestat[tile], (2 << 30) | (excl + aggregate));
    }
  }
  __syncthreads();
  int exclPrefix = (tile == 0) ? 0 : sPrefix;
  if (idx < N) {
    int o = exclPrefix + incl - c;
    rowptr[idx] = o;
    cursor[idx] = o;
  }
}

// CSR fill: erecA[p]={dis_r*attr, dx, dy, dz} (dis[cl] hoisted into k_edges), erecI[p]=row
__global__ void k_fill(const int* eidx, const int* flag, const float* attr, const float* dis,
                       const float* pos, int* cursor, float4* erecA, int* erecI, int E) {
  int e = blockIdx.x * 256 + threadIdx.x;
  if (e >= E) return;
  int is64 = *flag;
  int r  = load_idx(eidx, is64, e);
  int cl = load_idx(eidx, is64, (long long)E + e);
  float wr = dis[r] * attr[e];
  float dx = pos[cl * 3 + 0] - pos[r * 3 + 0];
  float dy = pos[cl * 3 + 1] - pos[r * 3 + 1];
  float dz = pos[cl * 3 + 2] - pos[r * 3 + 2];
  int p = atomicAdd(&cursor[cl], 1);
  erecA[p] = make_float4(wr, dx, dy, dz);
  erecI[p] = r;
}

// ---- fused MFMA node GEMM + degree atomics (independent work co-scheduled) ----
// blocks [0,GB): gemm v7 (512 thr, 32 nodes, split-bf16 MFMA, see r7 notes)
// blocks [GB,GB+DB): k_deg (one fp64 atomic per edge: dpk[col] += attr + 2^30)
__global__ __launch_bounds__(512, 4) void k_gemm_deg(
    const float* __restrict__ scalar, const float* __restrict__ vector,
    const u16* __restrict__ Wtg,
    uint4* __restrict__ rec_i4, uint4* __restrict__ rec_j4, int N, int GB,
    const int* __restrict__ eidx, const int* __restrict__ flag,
    const float* __restrict__ attr, double* __restrict__ dpk, int E) {
  __shared__ u32 smem[8192];          // 32 KB: A-tile, then reused as epilogue stage
  int tid = threadIdx.x;
  if ((int)blockIdx.x >= GB) {
    int e = ((int)blockIdx.x - GB) * 512 + tid;
    if (e < E) {
      int is64 = *flag;
      int col = load_idx(eidx, is64, (long long)E + e);
      atomicAdd(&dpk[col], (double)attr[e] + CNTSC);
    }
    return;
  }
  u16*   Ax = (u16*)smem;
  float* Ep = (float*)smem;
  int lane = tid & 63, wv = tid >> 6;
  int nb = blockIdx.x * 32;

  // ---- stage A: thread t: row = t>>2, 16 k's; convert fp32 -> bf16 hi/lo ----
  {
    int srow = tid >> 2, skq = tid & 3;
    const float* sp;
    int snode;
    if (srow < 32) { snode = nb + srow; sp = scalar + (size_t)snode * 64 + skq * 16; }
    else {
      int d = (srow - 32) >> 5, nl2 = (srow - 32) & 31;
      snode = nb + nl2;
      sp = vector + (size_t)snode * 192 + d * 64 + skq * 16;
    }
    bool valid = snode < N;
    u16 hi[16], lo[16];
    #pragma unroll
    for (int q = 0; q < 4; ++q) {
      float4 v = valid ? *(const float4*)(sp + 4 * q) : make_float4(0.f, 0.f, 0.f, 0.f);
      float xs[4] = {v.x, v.y, v.z, v.w};
      #pragma unroll
      for (int j = 0; j < 4; ++j) {
        u16 h = f2bf(xs[j]);
        hi[4 * q + j] = h;
        lo[4 * q + j] = f2bf(xs[j] - bf2f(h));
      }
    }
    int rs = srow & 7;
    #pragma unroll
    for (int c = 0; c < 2; ++c) {
      int lc = 2 * skq + c;
      uint4 wh, wl;
      wh.x = (u32)hi[8*c+0] | ((u32)hi[8*c+1] << 16);
      wh.y = (u32)hi[8*c+2] | ((u32)hi[8*c+3] << 16);
      wh.z = (u32)hi[8*c+4] | ((u32)hi[8*c+5] << 16);
      wh.w = (u32)hi[8*c+6] | ((u32)hi[8*c+7] << 16);
      wl.x = (u32)lo[8*c+0] | ((u32)lo[8*c+1] << 16);
      wl.y = (u32)lo[8*c+2] | ((u32)lo[8*c+3] << 16);
      wl.z = (u32)lo[8*c+4] | ((u32)lo[8*c+5] << 16);
      wl.w = (u32)lo[8*c+6] | ((u32)lo[8*c+7] << 16);
      *(uint4*)(Ax + srow * 128 + (lc ^ rs) * 8)        = wh;
      *(uint4*)(Ax + srow * 128 + ((8 + lc) ^ rs) * 8)  = wl;
    }
  }
  __syncthreads();

  // ---- MFMA main loop ----
  int c0 = wv * 32;
  int bl = lane & 15, bh = lane >> 4;
  f32x4 acc[8][2];
  #pragma unroll
  for (int mt = 0; mt < 8; ++mt)
    #pragma unroll
    for (int nt = 0; nt < 2; ++nt)
      acc[mt][nt] = (f32x4){0.f, 0.f, 0.f, 0.f};

  #pragma unroll
  for (int kh = 0; kh < 2; ++kh) {
    int k0 = kh * 32;
    bf16x8 Bh[2][2], Bl[2][2];
    #pragma unroll
    for (int rg = 0; rg < 2; ++rg)
      #pragma unroll
      for (int nt = 0; nt < 2; ++nt) {
        size_t rr = (size_t)(rg * 256 + c0 + nt * 16 + bl) * 128 + k0 + bh * 8;
        Bh[rg][nt] = *(const bf16x8*)(Wtg + rr);
        Bl[rg][nt] = *(const bf16x8*)(Wtg + rr + 64);
      }
    #pragma unroll
    for (int mt = 0; mt < 8; ++mt) {
      int row = mt * 16 + bl;
      int ch = (k0 >> 3) + bh, rs = row & 7;
      bf16x8 Ah = *(const bf16x8*)(Ax + row * 128 + (ch ^ rs) * 8);
      bf16x8 Al = *(const bf16x8*)(Ax + row * 128 + ((8 + ch) ^ rs) * 8);
      int rg = (mt < 2) ? 0 : 1;
      #pragma unroll
      for (int nt = 0; nt < 2; ++nt) {
        f32x4 a = acc[mt][nt];
        a = __builtin_amdgcn_mfma_f32_16x16x32_bf16(Ah, Bh[rg][nt], a, 0, 0, 0);
        a = __builtin_amdgcn_mfma_f32_16x16x32_bf16(Al, Bh[rg][nt], a, 0, 0, 0);
        a = __builtin_amdgcn_mfma_f32_16x16x32_bf16(Ah, Bl[rg][nt], a, 0, 0, 0);
        acc[mt][nt] = a;
      }
    }
  }

  // ---- epilogue: 4 passes (Gs, v0, v1, v2) through 32KB stage, pack uint4 ----
  int ech = tid & 63, eng = tid >> 6;
  uint4 oi[4], oj[4];
  #pragma unroll
  for (int pg = 0; pg < 4; ++pg) {
    __syncthreads();
    #pragma unroll
    for (int mm = 0; mm < 2; ++mm) {
      int mt = 2 * pg + mm;
      #pragma unroll
      for (int nt = 0; nt < 2; ++nt)
        #pragma unroll
        for (int r = 0; r < 4; ++r) {
          int rl = mm * 16 + bh * 4 + r;
          Ep[rl * 256 + c0 + nt * 16 + bl] = acc[mt][nt][r];
        }
    }
    __syncthreads();
    #pragma unroll
    for (int q = 0; q < 4; ++q) {
      int nl2 = eng + 8 * q;
      float vi0 = Ep[nl2 * 256 + ech];
      float vi1 = Ep[nl2 * 256 + 64 + ech];
      float vj0 = Ep[nl2 * 256 + 128 + ech];
      float vj1 = Ep[nl2 * 256 + 192 + ech];
      if (pg == 0) {
        oi[q].x = pk(vi0, vi1);                  oj[q].x = pk(vj0, vj1);
      } else if (pg == 1) {
        oi[q].y = (u32)f2bf(vi0);                oj[q].y = (u32)f2bf(vj0);
        oi[q].z = (u32)f2bf(vi1) << 16;          oj[q].z = (u32)f2bf(vj1) << 16;
      } else if (pg == 2) {
        oi[q].y |= (u32)f2bf(vi0) << 16;         oj[q].y |= (u32)f2bf(vj0) << 16;
        oi[q].w = (u32)f2bf(vi1);                oj[q].w = (u32)f2bf(vj1);
      } else {
        oi[q].z |= (u32)f2bf(vi0);               oj[q].z |= (u32)f2bf(vj0);
        oi[q].w |= (u32)f2bf(vi1) << 16;         oj[q].w |= (u32)f2bf(vj1) << 16;
      }
    }
  }
  #pragma unroll
  for (int q = 0; q < 4; ++q) {
    int node = nb + eng + 8 * q;
    if (node < N) {
      rec_i4[(size_t)node * 64 + ech] = oi[q];
      rec_j4[(size_t)node * 64 + ech] = oj[q];
    }
  }
}

// Fused hot kernel: one wave per node, wave-uniform scalar edge metadata,
// 2-edge unrolled loop with double prefetch, in-wave epilogue matvecs.
// Vector head fused across d (one pass over sWv, 3 accumulators).
__global__ __launch_bounds__(512) void k_edges(
    const u16* __restrict__ rec_i, const u16* __restrict__ rec_j,
    const float4* __restrict__ erecA, const int* __restrict__ erecI,
    const int* __restrict__ rowptr, const float* __restrict__ dis,
    const float* __restrict__ scalar, const float* __restrict__ vector,
    const float* __restrict__ bss, const float* __restrict__ bvs,
    const float* __restrict__ bsv, const float* __restrict__ bsl,
    const u32* __restrict__ Wsl2g, const u32* __restrict__ Wpkg,
    const float* __restrict__ bcg,
    float* __restrict__ out_s, float* __restrict__ out_v, int N) {
  __shared__ u32 sWsl[4096];        // 16 KB
  __shared__ u32 sWv[2048];         // 8 KB  (Wvl_right only)
  __shared__ float sStage[8 * 192]; // 6 KB, wave-private epilogue stage
  int tid = threadIdx.x, lane = tid & 63, wv = tid >> 6;
  for (int o = tid; o < 4096; o += 512) sWsl[o] = Wsl2g[o];
  for (int o = tid; o < 2048; o += 512) sWv[o] = Wpkg[o];
  __syncthreads();   // the only block barrier

  int node = __builtin_amdgcn_readfirstlane((int)(blockIdx.x * 8) + wv);
  if (node >= N) node = N - 1;

  uint4 riv = *(const uint4*)(rec_i + ((size_t)node << 9) + lane * 8);
  float aiB  = lo16(riv.x) + bss[lane];
  float KciB = TWOL2E * (hi16(riv.x) + bsv[lane]);
  float Bvs  = bvs[lane];
  float bib0 = lo16(riv.y) + Bvs;
  float bib1 = hi16(riv.y) + Bvs;
  float bib2 = lo16(riv.z) + Bvs;
  float Pi0  = hi16(riv.z), Pi1 = lo16(riv.w), Pi2 = hi16(riv.w);
  float bsl_c = bsl[lane], bc_c = bcg[lane];
  float disc = dis[node];

  float us = 0, uv = 0, t0 = 0, t1 = 0, t2 = 0, g0 = 0, g1 = 0, g2 = 0, wa = 0;
  int rp = rowptr[node], re = rowptr[node + 1];
  u32 lane16 = (u32)lane << 4;
  const char* rjb = (const char*)rec_j;

  // erecI has 64 zeroed ints of slack past E -> prefetch reads always valid
  u32 ra = (u32)erecI[rp];
  u32 rb = (u32)erecI[rp + 1];
  uint4 pre0 = *(const uint4*)(rjb + ((ra << 10) + lane16));
  uint4 pre1 = *(const uint4*)(rjb + ((rb << 10) + lane16));
  int p = rp;
  #define EDGE_MATH(CUR, EV)                                                  \
    {                                                                         \
      float nrm = EV.x, dx = EV.y, dy = EV.z, dz = EV.w;                      \
      float aj  = lo16(CUR.x), cj  = hi16(CUR.x);                             \
      float bj0 = lo16(CUR.y), bj1 = hi16(CUR.y), bj2 = lo16(CUR.z);          \
      float rj0 = hi16(CUR.z), rj1 = lo16(CUR.w), rj2 = hi16(CUR.w);          \
      float xs  = aiB + aj;                                                   \
      float s2s = xs * frcp(1.f + fexp2(xs * NL2E));                          \
      float yv  = (bib0 + bj0) * dx;                                          \
      yv = fmaf(bib1 + bj1, dy, yv);                                          \
      yv = fmaf(bib2 + bj2, dz, yv);                                          \
      float v2s = yv * frcp(1.f + fexp2(yv * NL2E));                          \
      float qh  = fmaf(TWOL2E, cj, KciB);                                     \
      float th0 = fmaf(-2.f, frcp(1.f + fexp2(qh * dx)), 1.f);                \
      float th1 = fmaf(-2.f, frcp(1.f + fexp2(qh * dy)), 1.f);                \
      float th2 = fmaf(-2.f, frcp(1.f + fexp2(qh * dz)), 1.f);                \
      us = fmaf(nrm, s2s, us); uv = fmaf(nrm, v2s, uv);                       \
      t0 = fmaf(nrm, th0, t0); t1 = fmaf(nrm, th1, t1); t2 = fmaf(nrm, th2, t2);\
      g0 = fmaf(nrm, rj0, g0); g1 = fmaf(nrm, rj1, g1); g2 = fmaf(nrm, rj2, g2);\
      wa += nrm;                                                              \
    }
  for (; p + 1 < re; p += 2) {
    uint4 cur0 = pre0, cur1 = pre1;
    u32 rn0 = (u32)erecI[p + 2];
    u32 rn1 = (u32)erecI[p + 3];
    pre0 = *(const uint4*)(rjb + ((rn0 << 10) + lane16));
    pre1 = *(const uint4*)(rjb + ((rn1 << 10) + lane16));
    float4 e0 = erecA[p];
    float4 e1 = erecA[p + 1];
    EDGE_MATH(cur0, e0)
    EDGE_MATH(cur1, e1)
  }
  if (p < re) {
    uint4 cur0 = pre0;
    float4 e0 = erecA[p];
    EDGE_MATH(cur0, e0)
  }
  #undef EDGE_MATH

  // scale by the wave-uniform dis[node] (hoisted out of per-edge nrm)
  us *= disc; uv *= disc;
  t0 *= disc; t1 *= disc; t2 *= disc;
  g0 *= disc; g1 *= disc; g2 *= disc;
  wa *= disc;

  // ---- epilogue: scalar head (wave-local, no block barrier) ----
  float* mys = &sStage[wv * 192];
  mys[lane] = us; mys[64 + lane] = uv;
  __threadfence_block();
  float acc = wa * bsl_c;
  #pragma unroll
  for (int g = 0; g < 32; ++g) {
    float4 u = *(const float4*)&mys[4 * g];
    uint2 w = *(const uint2*)&sWsl[(g * 64 + lane) * 2];
    acc = fmaf(u.x, lo16(w.x), acc);
    acc = fmaf(u.y, hi16(w.x), acc);
    acc = fmaf(u.z, lo16(w.y), acc);
    acc = fmaf(u.w, hi16(w.y), acc);
  }
  size_t so = ((size_t)node << 6) + lane;
  out_s[so] = acc * frcp(1.f + fexp2(acc * NL2E)) + scalar[so];

  // ---- epilogue: vector head, d-fused (one pass over sWv, 3 accumulators) ----
  __threadfence_block();
  mys[lane] = t0; mys[64 + lane] = t1; mys[128 + lane] = t2;
  __threadfence_block();
  float a20 = fmaf(wa, bc_c + Pi0, g0);
  float a21 = fmaf(wa, bc_c + Pi1, g1);
  float a22 = fmaf(wa, bc_c + Pi2, g2);
  #pragma unroll
  for (int g = 0; g < 16; ++g) {
    float4 u0 = *(const float4*)&mys[4 * g];
    float4 u1 = *(const float4*)&mys[64 + 4 * g];
    float4 u2 = *(const float4*)&mys[128 + 4 * g];
    uint2 w = *(const uint2*)&sWv[(g * 64 + lane) * 2];
    float w0 = lo16(w.x), w1 = hi16(w.x), w2 = lo16(w.y), w3 = hi16(w.y);
    a20 = fmaf(u0.x, w0, a20); a20 = fmaf(u0.y, w1, a20);
    a20 = fmaf(u0.z, w2, a20); a20 = fmaf(u0.w, w3, a20);
    a21 = fmaf(u1.x, w0, a21); a21 = fmaf(u1.y, w1, a21);
    a21 = fmaf(u1.z, w2, a21); a21 = fmaf(u1.w, w3, a21);
    a22 = fmaf(u2.x, w0, a22); a22 = fmaf(u2.y, w1, a22);
    a22 = fmaf(u2.z, w2, a22); a22 = fmaf(u2.w, w3, a22);
  }
  float a2v[3] = {a20, a21, a22};
  #pragma unroll
  for (int d = 0; d < 3; ++d) {
    size_t vo = (((size_t)node * 3 + d) << 6) + lane;
    float th = fmaf(-2.f, frcp(1.f + fexp2(TWOL2E * a2v[d])), 1.f);
    out_v[vo] = th + vector[vo];
  }
}

extern "C" void kernel_launch(void* const* d_in, const int* in_sizes, int n_in,
                              void* d_out, int out_size, void* d_ws, size_t ws_size,
                              hipStream_t stream) {
  const float* scalar   = (const float*)d_in[0];
  const float* vector   = (const float*)d_in[1];
  const float* position = (const float*)d_in[2];
  const int*   eidx     = (const int*)d_in[3];
  const float* attr     = (const float*)d_in[4];
  const float* Wss = (const float*)d_in[5];
  const float* bss = (const float*)d_in[6];
  const float* Wvs = (const float*)d_in[7];
  const float* bvs = (const float*)d_in[8];
  const float* Wsl = (const float*)d_in[9];
  const float* bsl = (const float*)d_in[10];
  const float* Wsv = (const float*)d_in[11];
  const float* bsv = (const float*)d_in[12];
  const float* Wvv = (const float*)d_in[13];
  const float* bvv = (const float*)d_in[14];
  const float* Wvl = (const float*)d_in[15];
  const float* bvl = (const float*)d_in[16];

  int N = in_sizes[0] / 64;
  int E = in_sizes[4];
  int NB = (N + 255) / 256;   // scan tiles

  char* wsb = (char*)d_ws;
  size_t off = 0;
  auto alloc = [&](size_t bytes) -> char* {
    char* p = wsb + off;
    off += (bytes + 255) & ~(size_t)255;
    return p;
  };
  double* dpk    = (double*)alloc((size_t)N * 8);
  int*    rowptr = (int*)alloc((size_t)(N + 1) * 4);
  int*    cursor = (int*)alloc((size_t)N * 4);
  float*  dis    = (float*)alloc((size_t)N * 4);
  int*    tilestat = (int*)alloc((size_t)NB * 4);
  int*    tilectr  = (int*)alloc(4);
  float4* erecA  = (float4*)alloc((size_t)E * 16);
  int*    erecI  = (int*)alloc((size_t)(E + 64) * 4);   // +slack for prefetch reads
  u16*    rec_i  = (u16*)alloc((size_t)N * 512 * 2);
  u16*    rec_j  = (u16*)alloc((size_t)N * 512 * 2);
  u16*    Wtg    = (u16*)alloc(512 * 128 * 2);          // 128 KB split-bf16 W^T
  u32*    Wsl2   = (u32*)alloc(4096 * 4);
  u32*    Wpk    = (u32*)alloc(2048 * 4);
  float*  WcTmp  = (float*)alloc(64 * 128 * 4);
  float*  bc     = (float*)alloc(64 * 4);
  int*    flag   = (int*)alloc(4);
  (void)ws_size; (void)n_in; (void)out_size;

  int GB = (N + 31) / 32;     // gemm blocks
  int DB = (E + 511) / 512;   // deg blocks

  k_prep1<<<35 + NB, 256, 0, stream>>>(Wvl, Wvv, bvv, bvl, eidx, E, flag,
                                       WcTmp, bc, dpk, erecI, tilestat, tilectr, N, NB);
  k_prep2<<<11, 256, 0, stream>>>(Wss, Wsv, Wvs, Wsl, Wvl, WcTmp, Wsl2, Wpk, Wtg);
  k_gemm_deg<<<GB + DB, 512, 0, stream>>>(scalar, vector, Wtg,
                                          (uint4*)rec_i, (uint4*)rec_j, N, GB,
                                          eidx, flag, attr, dpk, E);
  k_scan<<<NB, 256, 0, stream>>>(dpk, dis, rowptr, cursor, tilestat, tilectr, N, E);
  k_fill<<<(E + 255) / 256, 256, 0, stream>>>(eidx, flag, attr, dis, position, cursor, erecA, erecI, E);
  k_edges<<<(N + 7) / 8, 512, 0, stream>>>(rec_i, rec_j, erecA, erecI, rowptr, dis,
                                           scalar, vector, bss, bvs, bsv, bsl,
                                           Wsl2, Wpk, bc,
                                           (float*)d_out, (float*)d_out + (size_t)N * 64, N);
}